// Round 4
// baseline (968.925 us; speedup 1.0000x reference)
//
#include <hip/hip_runtime.h>
#include <cstdint>

// ============================================================================
// Supernetwork: conv-bn-relu-pool x3 backbone -> beam search -> expert dispatch
// R4: decision-critical math in fp64 (conv2/conv3 accumulators, all BN stats,
// beam logits/scores/h) so top-k decisions match the np/fp64 reference
// regardless of our summation order. Storage stays fp32. Output path
// (dispatch/head) stays fp32. All LDS pads zero-initialized.
// Layouts: CHW padded ([n][ci][h][Wpad]); weights [(ci*9+tap)*32+co].
// ============================================================================

// ---- ws layout (floats; doubles occupy 2 slots, all double offsets even) ----
static constexpr size_t O_SC    = 0;        // 192 doubles = 384 f: [sc|sh] x3 stages
static constexpr size_t O_W1T   = 512;      // 864 f
static constexpr size_t O_W2T   = 1408;     // 9216 f
static constexpr size_t O_W3T   = 10624;    // 9216 f
static constexpr size_t O_SCORES= 19840;    // 8192 doubles = 16384 f
static constexpr size_t O_P0    = 36224;    // 8192 f each
static constexpr size_t O_P1    = 44416;
static constexpr size_t O_P2    = 52608;
static constexpr size_t O_OP0   = 60800;    // int32
static constexpr size_t O_OP1   = 68992;
static constexpr size_t O_OP2   = 77184;
static constexpr size_t O_SRC1  = 85376;
static constexpr size_t O_SRC2  = 93568;
static constexpr size_t O_H0    = 101760;   // 2048*128
static constexpr size_t O_H     = 363904;   // 8192*128 (beam h / stats partials / HIDB)
static constexpr size_t O_H2    = 1412480;  // 8192*128
static constexpr size_t O_PART  = O_H;      // partials: <=2048*64 doubles = 262144 f
static constexpr size_t O_S1P   = 2461056;  // 2048*7680 [n][32][15][16]; dead after conv2
static constexpr size_t O_S3C   = O_S1P;    // 2048*512  [n][32][16] (S1P dead)
static constexpr size_t O_S2C   = 18189696; // 2048*6656 [n][32][13][16]; dead after conv3
static constexpr size_t O_HIDA  = O_S2C;    // 8192*128 (dispatch phase)
static constexpr size_t O_HIDB  = O_H;      // 8192*128 (beam dead by dispatch)
// total 31821184 floats = 127.3 MB

// ---------------------------------------------------------------------------
// K0: weights -> k-major [(ci*9+tap)*32 + co]
// ---------------------------------------------------------------------------
__global__ void prep_w(const float* __restrict__ w1, const float* __restrict__ w2,
                       const float* __restrict__ w3, float* __restrict__ w1t,
                       float* __restrict__ w2t, float* __restrict__ w3t) {
    int t = blockIdx.x * 256 + threadIdx.x;
    if (t < 864) {                       // w1 OIHW (32,3,3,3)
        int co = t / 27, k = t % 27;     // k = ci*9+tap
        w1t[k * 32 + co] = w1[t];
    }
    if (t < 9216) {                      // w2/w3 OIHW (32,32,3,3)
        int co = t / 288, k = t % 288;   // k = ci*9+tap
        w2t[k * 32 + co] = w2[t];
        w3t[k * 32 + co] = w3[t];
    }
}

// ---------------------------------------------------------------------------
// finalize_stats (fp64): reduce [nblocks][64] double partials -> sc/sh doubles
// ---------------------------------------------------------------------------
__global__ __launch_bounds__(256) void finalize_stats(
    const double* __restrict__ part, int nblocks, double invcount,
    const float* __restrict__ g, const float* __restrict__ be,
    double* __restrict__ scsh) {
    __shared__ double red[256];
    const int t = threadIdx.x;
    const int c = t & 63, grp = t >> 6;
    double s = 0.0;
    for (int i = grp; i < nblocks; i += 4) s += part[(size_t)i * 64 + c];
    red[t] = s;
    __syncthreads();
    if (t < 64) red[t] = red[t] + red[64 + t] + red[128 + t] + red[192 + t];
    __syncthreads();
    if (t < 32) {
        double mean = red[t] * invcount;
        double var = red[32 + t] * invcount - mean * mean;
        double sc = (double)g[t] / sqrt(var + 1e-5);
        scsh[t] = sc;
        scsh[32 + t] = (double)be[t] - mean * sc;
    }
}

// ---------------------------------------------------------------------------
// K1: conv1 stats. x LDS [ci][32][36] (pads zeroed). fp32 conv, fp64 sums.
// Thread task = 4 conv px (row) x 8 ch; 960 tasks.
// ---------------------------------------------------------------------------
__global__ __launch_bounds__(256) void conv1_stats_kernel(
    const float* __restrict__ x, const float* __restrict__ w1t,
    double* __restrict__ part) {
    __shared__ float xs[3456];
    __shared__ float wt[864];
    __shared__ double red[4][2][32];
    const int n = blockIdx.x, t = threadIdx.x;
    const float* xin = x + (size_t)n * 3072;
    for (int i = t; i < 3072; i += 256) {
        int ci = i >> 10, rem = i & 1023;
        xs[ci * 1152 + (rem >> 5) * 36 + (rem & 31)] = xin[i];
    }
    for (int i = t; i < 384; i += 256) {           // zero pad cols 32..35
        int ci = i >> 7, rem = i & 127;
        xs[ci * 1152 + (rem >> 2) * 36 + 32 + (rem & 3)] = 0.f;
    }
    for (int i = t; i < 864; i += 256) wt[i] = w1t[i];
    __syncthreads();
    const int cg = t & 3, c0 = cg * 8;
    double sm[8] = {}, sq[8] = {};
    for (int task = t; task < 960; task += 256) {
        const int chunk = task >> 2;
        const int r = chunk >> 3, wc = (chunk & 7) * 4;
        float acc[4][8] = {};
        for (int ci = 0; ci < 3; ++ci) {
            float v[3][6];
#pragma unroll
            for (int rr = 0; rr < 3; ++rr) {
                const float* p = &xs[ci * 1152 + (r + rr) * 36 + wc];
                float4 a = *(const float4*)p;
                float2 b = *(const float2*)(p + 4);
                v[rr][0] = a.x; v[rr][1] = a.y; v[rr][2] = a.z; v[rr][3] = a.w;
                v[rr][4] = b.x; v[rr][5] = b.y;
            }
#pragma unroll
            for (int th = 0; th < 3; ++th)
#pragma unroll
            for (int tw = 0; tw < 3; ++tw) {
                const float* wp = &wt[(ci * 9 + th * 3 + tw) * 32 + c0];
                float4 wa = *(const float4*)wp;
                float4 wb = *(const float4*)(wp + 4);
                float w8[8] = {wa.x, wa.y, wa.z, wa.w, wb.x, wb.y, wb.z, wb.w};
#pragma unroll
                for (int j = 0; j < 4; ++j) {
                    float xv = v[th][j + tw];
#pragma unroll
                    for (int c = 0; c < 8; ++c) acc[j][c] += xv * w8[c];
                }
            }
        }
#pragma unroll
        for (int j = 0; j < 4; ++j) {
            if (wc + j < 30) {
#pragma unroll
                for (int c = 0; c < 8; ++c) {
                    double y = (double)acc[j][c];
                    sm[c] += y; sq[c] += y * y;
                }
            }
        }
    }
#pragma unroll
    for (int m = 4; m <= 32; m <<= 1)
#pragma unroll
        for (int c = 0; c < 8; ++c) {
            sm[c] += __shfl_xor(sm[c], m);
            sq[c] += __shfl_xor(sq[c], m);
        }
    const int wv = t >> 6, lane = t & 63;
    if (lane < 4) {
#pragma unroll
        for (int c = 0; c < 8; ++c) {
            red[wv][0][lane * 8 + c] = sm[c];
            red[wv][1][lane * 8 + c] = sq[c];
        }
    }
    __syncthreads();
    if (t < 64) {
        int which = t >> 5, ch = t & 31;
        part[(size_t)n * 64 + t] = red[0][which][ch] + red[1][which][ch] +
                                   red[2][which][ch] + red[3][which][ch];
    }
}

// ---------------------------------------------------------------------------
// K2: conv1(fp32) + BN(fp64 scale)+relu+pool -> s1p [n][32][15][16].
// Thread = 2 pooled px x 8 ch. Col 15 explicitly zeroed.
// ---------------------------------------------------------------------------
__global__ __launch_bounds__(512) void conv1_apply_kernel(
    const float* __restrict__ x, const float* __restrict__ w1t,
    const double* __restrict__ scsh, float* __restrict__ s1p) {
    __shared__ float xs[3456];
    __shared__ float wt[864];
    __shared__ double bn[64];
    const int n = blockIdx.x, t = threadIdx.x;
    const float* xin = x + (size_t)n * 3072;
    for (int i = t; i < 3072; i += 512) {
        int ci = i >> 10, rem = i & 1023;
        xs[ci * 1152 + (rem >> 5) * 36 + (rem & 31)] = xin[i];
    }
    for (int i = t; i < 384; i += 512) {
        int ci = i >> 7, rem = i & 127;
        xs[ci * 1152 + (rem >> 2) * 36 + 32 + (rem & 3)] = 0.f;
    }
    for (int i = t; i < 864; i += 512) wt[i] = w1t[i];
    if (t < 64) bn[t] = scsh[t];
    __syncthreads();
    const bool act = t < 480;
    const int cg = t & 3, c0 = cg * 8;
    const int chunk = act ? (t >> 2) : 119;
    const int ph = chunk >> 3, pw0 = (chunk & 7) * 2;
    const int xr = 2 * ph, xw = 2 * pw0;
    float acc[2][4][8] = {};
    for (int ci = 0; ci < 3; ++ci) {
        float v[4][6];
#pragma unroll
        for (int rr = 0; rr < 4; ++rr) {
            const float* p = &xs[ci * 1152 + (xr + rr) * 36 + xw];
            float4 a = *(const float4*)p;
            float2 b = *(const float2*)(p + 4);
            v[rr][0] = a.x; v[rr][1] = a.y; v[rr][2] = a.z; v[rr][3] = a.w;
            v[rr][4] = b.x; v[rr][5] = b.y;
        }
#pragma unroll
        for (int th = 0; th < 3; ++th)
#pragma unroll
        for (int tw = 0; tw < 3; ++tw) {
            const float* wp = &wt[(ci * 9 + th * 3 + tw) * 32 + c0];
            float4 wa = *(const float4*)wp;
            float4 wb = *(const float4*)(wp + 4);
            float w8[8] = {wa.x, wa.y, wa.z, wa.w, wb.x, wb.y, wb.z, wb.w};
#pragma unroll
            for (int rr = 0; rr < 2; ++rr)
#pragma unroll
            for (int ww = 0; ww < 4; ++ww) {
                float xv = v[rr + th][ww + tw];
#pragma unroll
                for (int c = 0; c < 8; ++c) acc[rr][ww][c] += xv * w8[c];
            }
        }
    }
    if (act) {
#pragma unroll
        for (int c = 0; c < 8; ++c) {
            double s = bn[c0 + c], h = bn[32 + c0 + c];
            double p0 = 0.25 * (fmax((double)acc[0][0][c] * s + h, 0.0) +
                                fmax((double)acc[0][1][c] * s + h, 0.0) +
                                fmax((double)acc[1][0][c] * s + h, 0.0) +
                                fmax((double)acc[1][1][c] * s + h, 0.0));
            double p1 = 0.25 * (fmax((double)acc[0][2][c] * s + h, 0.0) +
                                fmax((double)acc[0][3][c] * s + h, 0.0) +
                                fmax((double)acc[1][2][c] * s + h, 0.0) +
                                fmax((double)acc[1][3][c] * s + h, 0.0));
            float p1s = (pw0 < 14) ? (float)p1 : 0.f;   // col 15 = 0
            float* dst = s1p + (size_t)n * 7680 + (c0 + c) * 240 + ph * 16 + pw0;
            *(float2*)dst = make_float2((float)p0, p1s);
        }
    }
}

// ---------------------------------------------------------------------------
// K3: conv2 (fp64 acc) [n][32][15][16]->[n][32][13][16] (pads stored 0).
// Thread = 4 consec-w px x 8 ch. In-kernel fp64 stats partials.
// ---------------------------------------------------------------------------
__global__ __launch_bounds__(256) void conv2_kernel(
    const float* __restrict__ s1p, const float* __restrict__ w2t,
    float* __restrict__ s2c, double* __restrict__ part) {
    __shared__ float img[7684];
    __shared__ float wt[4608];
    __shared__ double red[4][2][32];
    const int n = blockIdx.x, t = threadIdx.x;
    {
        const float4* src = (const float4*)(s1p + (size_t)n * 7680);
        float4* d = (float4*)img;
        for (int i = t; i < 1920; i += 256) d[i] = src[i];
        if (t < 4) img[7680 + t] = 0.f;            // zero guard
    }
    const bool act = t < 208;
    const int cg = t & 3, c0 = cg * 8;
    const int chunk = act ? (t >> 2) : 51;
    const int oh = chunk >> 2, ow = (chunk & 3) * 4;
    double acc[4][8] = {};
    for (int phs = 0; phs < 2; ++phs) {
        __syncthreads();
        for (int i = t; i < 4608; i += 256) wt[i] = w2t[phs * 4608 + i];
        __syncthreads();
        for (int ci = 0; ci < 16; ++ci) {
            const int cig = phs * 16 + ci;
#pragma unroll
            for (int th = 0; th < 3; ++th) {
                const float* ip = &img[cig * 240 + (oh + th) * 16 + ow];
                float4 a = *(const float4*)ip;
                float4 b = *(const float4*)(ip + 4);
                double v[8] = {a.x, a.y, a.z, a.w, b.x, b.y, b.z, b.w};
#pragma unroll
                for (int tw = 0; tw < 3; ++tw) {
                    const float* wp = &wt[(ci * 9 + th * 3 + tw) * 32 + c0];
                    float4 wa = *(const float4*)wp;
                    float4 wb = *(const float4*)(wp + 4);
                    double w8[8] = {wa.x, wa.y, wa.z, wa.w, wb.x, wb.y, wb.z, wb.w};
#pragma unroll
                    for (int j = 0; j < 4; ++j) {
                        double xv = v[j + tw];
#pragma unroll
                        for (int c = 0; c < 8; ++c) acc[j][c] += xv * w8[c];
                    }
                }
            }
        }
    }
#pragma unroll
    for (int j = 0; j < 4; ++j) {
        bool valid = act && (ow + j < 13);
        if (!valid) {
#pragma unroll
            for (int c = 0; c < 8; ++c) acc[j][c] = 0.0;
        }
    }
    if (act) {
#pragma unroll
        for (int c = 0; c < 8; ++c) {
            float* dst = s2c + (size_t)n * 6656 + (c0 + c) * 208 + oh * 16 + ow;
            *(float4*)dst = make_float4((float)acc[0][c], (float)acc[1][c],
                                        (float)acc[2][c], (float)acc[3][c]);
        }
    }
    double sm[8], sq[8];
#pragma unroll
    for (int c = 0; c < 8; ++c) {
        sm[c] = acc[0][c] + acc[1][c] + acc[2][c] + acc[3][c];
        sq[c] = acc[0][c] * acc[0][c] + acc[1][c] * acc[1][c] +
                acc[2][c] * acc[2][c] + acc[3][c] * acc[3][c];
    }
#pragma unroll
    for (int m = 4; m <= 32; m <<= 1)
#pragma unroll
        for (int c = 0; c < 8; ++c) {
            sm[c] += __shfl_xor(sm[c], m);
            sq[c] += __shfl_xor(sq[c], m);
        }
    const int wv = t >> 6, lane = t & 63;
    if (lane < 4) {
#pragma unroll
        for (int c = 0; c < 8; ++c) {
            red[wv][0][lane * 8 + c] = sm[c];
            red[wv][1][lane * 8 + c] = sq[c];
        }
    }
    __syncthreads();
    if (t < 64) {
        int which = t >> 5, ch = t & 31;
        part[(size_t)n * 64 + t] = red[0][which][ch] + red[1][which][ch] +
                                   red[2][which][ch] + red[3][which][ch];
    }
}

// ---------------------------------------------------------------------------
// K4: conv3 (fp64 acc) with fused BN2(fp64)+relu+pool2 staging. 8 img/block.
// img [im][ci][6][8] (cols 6,7 = 0). Out s3c [n][32][16] + fp64 stats.
// ---------------------------------------------------------------------------
__global__ __launch_bounds__(128) void conv3_kernel(
    const float* __restrict__ s2c, const float* __restrict__ w3t,
    const double* __restrict__ scsh2, float* __restrict__ s3c,
    double* __restrict__ part) {
    __shared__ float img[12288];
    __shared__ float wt[4608];
    __shared__ double red[2][2][32];
    const int n0 = blockIdx.x * 8, t = threadIdx.x;
    for (int i = t; i < 12288; i += 128) {
        int im = i / 1536, rem = i % 1536;
        int ci = rem / 48, r2 = rem % 48;
        int h = r2 >> 3, w = r2 & 7;
        float val = 0.f;
        if (w < 6) {
            const float* b = s2c + (size_t)(n0 + im) * 6656 + ci * 208 +
                             (2 * h) * 16 + 2 * w;
            double s = scsh2[ci], hh = scsh2[32 + ci];
            double a0 = fmax((double)b[0] * s + hh, 0.0);
            double a1 = fmax((double)b[1] * s + hh, 0.0);
            double a2 = fmax((double)b[16] * s + hh, 0.0);
            double a3 = fmax((double)b[17] * s + hh, 0.0);
            val = (float)(0.25 * (a0 + a1 + a2 + a3));
        }
        img[i] = val;
    }
    const int im = t >> 4, rem = t & 15;
    const int oh = rem >> 2, cg = rem & 3, c0 = cg * 8;
    double acc[4][8] = {};
    for (int phs = 0; phs < 2; ++phs) {
        __syncthreads();
        for (int i = t; i < 4608; i += 128) wt[i] = w3t[phs * 4608 + i];
        __syncthreads();
        for (int ci = 0; ci < 16; ++ci) {
            const int cig = phs * 16 + ci;
#pragma unroll
            for (int th = 0; th < 3; ++th) {
                const float* ip = &img[im * 1536 + cig * 48 + (oh + th) * 8];
                float4 a = *(const float4*)ip;
                float4 b = *(const float4*)(ip + 4);
                double v[8] = {a.x, a.y, a.z, a.w, b.x, b.y, b.z, b.w};
#pragma unroll
                for (int tw = 0; tw < 3; ++tw) {
                    const float* wp = &wt[(ci * 9 + th * 3 + tw) * 32 + c0];
                    float4 wa = *(const float4*)wp;
                    float4 wb = *(const float4*)(wp + 4);
                    double w8[8] = {wa.x, wa.y, wa.z, wa.w, wb.x, wb.y, wb.z, wb.w};
#pragma unroll
                    for (int j = 0; j < 4; ++j) {
                        double xv = v[j + tw];
#pragma unroll
                        for (int c = 0; c < 8; ++c) acc[j][c] += xv * w8[c];
                    }
                }
            }
        }
    }
#pragma unroll
    for (int c = 0; c < 8; ++c) {
        float* dst = s3c + (size_t)(n0 + im) * 512 + (c0 + c) * 16 + oh * 4;
        *(float4*)dst = make_float4((float)acc[0][c], (float)acc[1][c],
                                    (float)acc[2][c], (float)acc[3][c]);
    }
    double sm[8], sq[8];
#pragma unroll
    for (int c = 0; c < 8; ++c) {
        sm[c] = acc[0][c] + acc[1][c] + acc[2][c] + acc[3][c];
        sq[c] = acc[0][c] * acc[0][c] + acc[1][c] * acc[1][c] +
                acc[2][c] * acc[2][c] + acc[3][c] * acc[3][c];
    }
#pragma unroll
    for (int m = 4; m <= 32; m <<= 1)
#pragma unroll
        for (int c = 0; c < 8; ++c) {
            sm[c] += __shfl_xor(sm[c], m);
            sq[c] += __shfl_xor(sq[c], m);
        }
    const int wv = t >> 6, lane = t & 63;
    if (lane < 4) {
#pragma unroll
        for (int c = 0; c < 8; ++c) {
            red[wv][0][lane * 8 + c] = sm[c];
            red[wv][1][lane * 8 + c] = sq[c];
        }
    }
    __syncthreads();
    if (t < 64) {
        int which = t >> 5, ch = t & 31;
        part[(size_t)blockIdx.x * 64 + t] = red[0][which][ch] + red[1][which][ch];
    }
}

// ---------------------------------------------------------------------------
// K5: BN3(fp64)+relu+pool3 -> h0 (fp32) NCHW-flat h0[n][c*4+ph*2+pw]
// ---------------------------------------------------------------------------
__global__ void bn_pool3_h0(const float* __restrict__ s3c,
                            const double* __restrict__ scsh,
                            float* __restrict__ h0) {
    __shared__ double bn[64];
    const int t = threadIdx.x;
    if (t < 64) bn[t] = scsh[t];
    __syncthreads();
    const int idx = blockIdx.x * 256 + t;
    if (idx >= 262144) return;
    const int n = idx >> 7, rem = idx & 127;
    const int c = rem >> 2, q = rem & 3, ph = q >> 1, pw = q & 1;
    const float* b = s3c + (size_t)n * 512 + c * 16 + (2 * ph) * 4 + 2 * pw;
    const double s = bn[c], h = bn[32 + c];
    double a0 = fmax((double)b[0] * s + h, 0.0);
    double a1 = fmax((double)b[1] * s + h, 0.0);
    double a2 = fmax((double)b[4] * s + h, 0.0);
    double a3 = fmax((double)b[5] * s + h, 0.0);
    h0[idx] = (float)(0.25 * (a0 + a1 + a2 + a3));
}

// ---------------------------------------------------------------------------
// K6: beam level 0 (fp64 logits/softmax/scores). One wave per sample.
// ---------------------------------------------------------------------------
__global__ void beam0_kernel(const float* __restrict__ h0, const float* __restrict__ Who,
                             const float* __restrict__ bho, double* __restrict__ scores,
                             int* __restrict__ op0, float* __restrict__ p0) {
    const int n = blockIdx.x, lane = threadIdx.x;
    const float* hr = h0 + (size_t)n * 128;
    double pt[4] = {};
    for (int i = lane; i < 128; i += 64) {
        double hv = hr[i];
        pt[0] += hv * (double)Who[i * 4 + 0];
        pt[1] += hv * (double)Who[i * 4 + 1];
        pt[2] += hv * (double)Who[i * 4 + 2];
        pt[3] += hv * (double)Who[i * 4 + 3];
    }
#pragma unroll
    for (int off = 32; off > 0; off >>= 1)
#pragma unroll
        for (int o = 0; o < 4; ++o) pt[o] += __shfl_down(pt[o], off);
    if (lane == 0) {
        double lg[4], e[4], probs[4], logp[4];
#pragma unroll
        for (int o = 0; o < 4; ++o) lg[o] = pt[o] + (double)bho[o];
        double m = fmax(fmax(lg[0], lg[1]), fmax(lg[2], lg[3]));
        double sum = 0.0;
#pragma unroll
        for (int o = 0; o < 4; ++o) { e[o] = exp(lg[o] - m); sum += e[o]; }
        double lse = log(sum);
#pragma unroll
        for (int o = 0; o < 4; ++o) {
            probs[o] = e[o] / sum;
            logp[o] = lg[o] - m - lse;
        }
        bool used[4] = {false, false, false, false};
        for (int slot = 0; slot < 4; ++slot) {
            int best = 0; double bv = -INFINITY;
            for (int o = 0; o < 4; ++o)
                if (!used[o] && logp[o] > bv) { bv = logp[o]; best = o; }
            used[best] = true;
            scores[n * 4 + slot] = bv;
            op0[n * 4 + slot] = best;
            p0[n * 4 + slot] = (float)probs[best];
        }
    }
}

// ---------------------------------------------------------------------------
// K8/K10: beam level >=1 (fp64). One wave per sample.
// ---------------------------------------------------------------------------
__global__ void beam_level(const float* __restrict__ h, const float* __restrict__ Who,
                           const float* __restrict__ bho, double* __restrict__ scores,
                           int* __restrict__ opL, float* __restrict__ pL,
                           int* __restrict__ srcL) {
    __shared__ double logits[16], cand[16], pr[16];
    const int n = blockIdx.x, l = threadIdx.x;
    const int b = l >> 4, o = (l >> 2) & 3, qt = l & 3;
    const float* hr = h + ((size_t)n * 4 + b) * 128;
    double s = 0.0;
    for (int k = qt * 32; k < qt * 32 + 32; ++k)
        s += (double)hr[k] * (double)Who[k * 4 + o];
    s += __shfl_xor(s, 1);
    s += __shfl_xor(s, 2);
    if (qt == 0) logits[b * 4 + o] = s + (double)bho[o];
    __syncthreads();
    if (l < 4) {
        double lg[4];
#pragma unroll
        for (int o2 = 0; o2 < 4; ++o2) lg[o2] = logits[l * 4 + o2];
        double m = fmax(fmax(lg[0], lg[1]), fmax(lg[2], lg[3]));
        double e[4], sum = 0.0;
#pragma unroll
        for (int o2 = 0; o2 < 4; ++o2) { e[o2] = exp(lg[o2] - m); sum += e[o2]; }
        double lse = log(sum);
        double sb = scores[n * 4 + l];
#pragma unroll
        for (int o2 = 0; o2 < 4; ++o2) {
            pr[l * 4 + o2] = e[o2] / sum;
            cand[l * 4 + o2] = sb + (lg[o2] - m - lse);
        }
    }
    __syncthreads();
    if (l == 0) {
        bool used[16];
#pragma unroll
        for (int f = 0; f < 16; ++f) used[f] = false;
        double ns[4]; float np[4]; int nop[4], nsrc[4];
        for (int slot = 0; slot < 4; ++slot) {
            int best = 0; double bv = -INFINITY;
            for (int f = 0; f < 16; ++f)
                if (!used[f] && cand[f] > bv) { bv = cand[f]; best = f; }
            used[best] = true;
            ns[slot] = bv; nsrc[slot] = best >> 2; nop[slot] = best & 3;
            np[slot] = (float)pr[best];
        }
        for (int slot = 0; slot < 4; ++slot) {
            scores[n * 4 + slot] = ns[slot];
            opL[n * 4 + slot] = nop[slot];
            pL[n * 4 + slot] = np[slot];
            srcL[n * 4 + slot] = nsrc[slot];
        }
    }
}

// ---------------------------------------------------------------------------
// K7/K9: h = tanh(src @ W_hh + E_op[op] + b_h) in fp64; h stored fp32.
// ---------------------------------------------------------------------------
__global__ __launch_bounds__(256) void h_update(
    const float* __restrict__ in, int mode, const int* __restrict__ srcL,
    const int* __restrict__ opL, const float* __restrict__ Whh,
    const float* __restrict__ Eop, const float* __restrict__ bh,
    float* __restrict__ out) {
    __shared__ float A[256];
    const int r0 = blockIdx.x * 2, t = threadIdx.x;
    const int row = t >> 7, j = t & 127;
    const int r = r0 + row;
    const float* src;
    if (mode == 0) src = in + (size_t)(r >> 2) * 128;
    else           src = in + (size_t)((r & ~3) + srcL[r]) * 128;
    A[t] = src[j];
    __syncthreads();
    double acc = 0.0;
#pragma unroll 8
    for (int k = 0; k < 128; ++k)
        acc += (double)A[row * 128 + k] * (double)Whh[k * 128 + j];
    out[(size_t)r * 128 + j] =
        (float)tanh(acc + (double)Eop[opL[r] * 128 + j] + (double)bh[j]);
}

// ---------------------------------------------------------------------------
// K11-13: dispatch (fp32 output path): selected expert (op<3) or identity.
// ---------------------------------------------------------------------------
__global__ __launch_bounds__(256) void dispatch_kernel(
    const float* __restrict__ in, int mode, const int* __restrict__ opL,
    const float* __restrict__ pL, const float* __restrict__ expw,
    const float* __restrict__ expb, float* __restrict__ out) {
    __shared__ float A[256];
    const int r0 = blockIdx.x * 2, t = threadIdx.x;
    const int row = t >> 7, j = t & 127;
    const int r = r0 + row;
    const float* src = (mode == 0) ? in + (size_t)(r >> 2) * 128
                                   : in + (size_t)r * 128;
    A[t] = src[j];
    __syncthreads();
    const int op = opL[r];
    const float p = pL[r];
    float res;
    if (op < 3) {
        const float* Bw = expw + (size_t)op * 16384;
        float acc = 0.f;
#pragma unroll 8
        for (int k = 0; k < 128; ++k) acc += A[row * 128 + k] * Bw[k * 128 + j];
        res = (acc + expb[op * 128 + j]) * p;
    } else {
        res = A[row * 128 + j] * p;
    }
    out[(size_t)r * 128 + j] = fmaxf(res, 0.f);
}

// ---------------------------------------------------------------------------
// K14: final head (8192 x 10), fp32
// ---------------------------------------------------------------------------
__global__ void final_kernel(const float* __restrict__ hid, const float* __restrict__ ow,
                             const float* __restrict__ ob, float* __restrict__ out) {
    const int idx = blockIdx.x * 256 + threadIdx.x;
    if (idx >= 81920) return;
    const int r = idx / 10, o = idx % 10;
    const float* hr = hid + (size_t)r * 128;
    float acc = ob[o];
#pragma unroll 8
    for (int k = 0; k < 128; ++k) acc += hr[k] * ow[k * 10 + o];
    out[idx] = acc;
}

// ===========================================================================
extern "C" void kernel_launch(void* const* d_in, const int* in_sizes, int n_in,
                              void* d_out, int out_size, void* d_ws, size_t ws_size,
                              hipStream_t stream) {
    const float* x    = (const float*)d_in[0];
    const float* cw1  = (const float*)d_in[1];
    const float* g1   = (const float*)d_in[3];
    const float* be1  = (const float*)d_in[4];
    const float* cw2  = (const float*)d_in[5];
    const float* g2   = (const float*)d_in[7];
    const float* be2  = (const float*)d_in[8];
    const float* cw3  = (const float*)d_in[9];
    const float* g3   = (const float*)d_in[11];
    const float* be3  = (const float*)d_in[12];
    const float* Whh  = (const float*)d_in[13];
    const float* bh   = (const float*)d_in[14];
    const float* Eop  = (const float*)d_in[15];
    const float* Who  = (const float*)d_in[16];
    const float* bho  = (const float*)d_in[17];
    const float* expw = (const float*)d_in[18];
    const float* expb = (const float*)d_in[19];
    const float* outw = (const float*)d_in[20];
    const float* outb = (const float*)d_in[21];
    float*  ws    = (float*)d_ws;
    float*  out   = (float*)d_out;
    double* scsh  = (double*)(ws + O_SC);       // [64]x3 stages
    double* part  = (double*)(ws + O_PART);
    double* score = (double*)(ws + O_SCORES);

    prep_w<<<36, 256, 0, stream>>>(cw1, cw2, cw3, ws + O_W1T, ws + O_W2T, ws + O_W3T);

    // ---- backbone ----
    conv1_stats_kernel<<<2048, 256, 0, stream>>>(x, ws + O_W1T, part);
    finalize_stats<<<1, 256, 0, stream>>>(part, 2048, 1.0 / 1843200.0, g1, be1, scsh);
    conv1_apply_kernel<<<2048, 512, 0, stream>>>(x, ws + O_W1T, scsh, ws + O_S1P);
    conv2_kernel<<<2048, 256, 0, stream>>>(ws + O_S1P, ws + O_W2T, ws + O_S2C, part);
    finalize_stats<<<1, 256, 0, stream>>>(part, 2048, 1.0 / 346112.0, g2, be2, scsh + 64);
    conv3_kernel<<<256, 128, 0, stream>>>(ws + O_S2C, ws + O_W3T, scsh + 64,
                                          ws + O_S3C, part);
    finalize_stats<<<1, 256, 0, stream>>>(part, 256, 1.0 / 32768.0, g3, be3, scsh + 128);
    bn_pool3_h0<<<1024, 256, 0, stream>>>(ws + O_S3C, scsh + 128, ws + O_H0);

    // ---- beam search ----
    beam0_kernel<<<2048, 64, 0, stream>>>(ws + O_H0, Who, bho, score,
                                          (int*)(ws + O_OP0), ws + O_P0);
    h_update<<<4096, 256, 0, stream>>>(ws + O_H0, 0, (int*)(ws + O_SRC2),
                                       (int*)(ws + O_OP0), Whh, Eop, bh, ws + O_H);
    beam_level<<<2048, 64, 0, stream>>>(ws + O_H, Who, bho, score,
                                        (int*)(ws + O_OP1), ws + O_P1,
                                        (int*)(ws + O_SRC1));
    h_update<<<4096, 256, 0, stream>>>(ws + O_H, 1, (int*)(ws + O_SRC1),
                                       (int*)(ws + O_OP1), Whh, Eop, bh, ws + O_H2);
    beam_level<<<2048, 64, 0, stream>>>(ws + O_H2, Who, bho, score,
                                        (int*)(ws + O_OP2), ws + O_P2,
                                        (int*)(ws + O_SRC2));

    // ---- expert dispatch (3 rounds) + head ----
    dispatch_kernel<<<4096, 256, 0, stream>>>(ws + O_H0, 0, (int*)(ws + O_OP0),
                                              ws + O_P0, expw, expb, ws + O_HIDA);
    dispatch_kernel<<<4096, 256, 0, stream>>>(ws + O_HIDA, 1, (int*)(ws + O_OP1),
                                              ws + O_P1, expw, expb, ws + O_HIDB);
    dispatch_kernel<<<4096, 256, 0, stream>>>(ws + O_HIDB, 1, (int*)(ws + O_OP2),
                                              ws + O_P2, expw, expb, ws + O_HIDA);
    final_kernel<<<320, 256, 0, stream>>>(ws + O_HIDA, outw, outb, out);
}

// Round 6
// 933.609 us; speedup vs baseline: 1.0378x; 1.0378x over previous
//
#include <hip/hip_runtime.h>
#include <cstdint>

// ============================================================================
// Supernetwork: conv-bn-relu-pool x3 backbone -> beam search -> expert dispatch
// R6: fixes R5's crash — dispatch As-staging index decomposition was
// (i>>3, i&7) for a 32x128 tile (row ran to 127 -> LDS OOB write -> abort);
// correct is (i>>5, i&31). No other changes vs R5:
// (a) conv2 = fp32 9-MAC per-ci chains flushed to fp64; (b) h0_update computes
// per-sample h0@Whh once; (c) op-sorted dispatch w/ LDS-staged expert weights,
// round 3 fuses the 10-col head. BN stats / beam scores / conv3 stay fp64.
// ============================================================================

// ---- ws layout (floats; doubles occupy 2 slots, all double offsets even) ----
static constexpr size_t O_SC    = 0;        // 192 doubles = 384 f
static constexpr size_t O_W1T   = 512;      // 864 f
static constexpr size_t O_W2T   = 1408;     // 9216 f
static constexpr size_t O_W3T   = 10624;    // 9216 f
static constexpr size_t O_SCORES= 19840;    // 8192 doubles
static constexpr size_t O_P0    = 36224;    // 8192 f each
static constexpr size_t O_P1    = 44416;
static constexpr size_t O_P2    = 52608;
static constexpr size_t O_OP0   = 60800;    // int32
static constexpr size_t O_OP1   = 68992;
static constexpr size_t O_OP2   = 77184;
static constexpr size_t O_SRC1  = 85376;
static constexpr size_t O_SRC2  = 93568;
static constexpr size_t O_H0    = 101760;   // 2048*128
static constexpr size_t O_H     = 363904;   // 8192*128 (beam h / partials / HIDB)
static constexpr size_t O_H2    = 1412480;  // 8192*128 (beam h2 / sort tables)
static constexpr size_t O_PART  = O_H;
static constexpr size_t O_S1P   = 2461056;  // 2048*7680; dead after conv2
static constexpr size_t O_S3C   = O_S1P;    // 2048*512
static constexpr size_t O_S2C   = 18189696; // 2048*6656; dead after conv3
static constexpr size_t O_HIDA  = O_S2C;
static constexpr size_t O_HIDB  = O_H;
// sort tables live in the (dead-after-beam) H2 region:
static constexpr size_t O_PERM  = O_H2;             // 3*8192 int
static constexpr size_t O_BLKOP = O_H2 + 24576;     // 3*272 int
static constexpr size_t O_BLKST = O_H2 + 25392;     // 3*272 int
static constexpr size_t O_BLKCT = O_H2 + 26208;     // 3*272 int

// ---------------------------------------------------------------------------
// K0: weights -> k-major [(ci*9+tap)*32 + co]
// ---------------------------------------------------------------------------
__global__ void prep_w(const float* __restrict__ w1, const float* __restrict__ w2,
                       const float* __restrict__ w3, float* __restrict__ w1t,
                       float* __restrict__ w2t, float* __restrict__ w3t) {
    int t = blockIdx.x * 256 + threadIdx.x;
    if (t < 864) {
        int co = t / 27, k = t % 27;
        w1t[k * 32 + co] = w1[t];
    }
    if (t < 9216) {
        int co = t / 288, k = t % 288;
        w2t[k * 32 + co] = w2[t];
        w3t[k * 32 + co] = w3[t];
    }
}

// ---------------------------------------------------------------------------
// finalize_stats (fp64)
// ---------------------------------------------------------------------------
__global__ __launch_bounds__(256) void finalize_stats(
    const double* __restrict__ part, int nblocks, double invcount,
    const float* __restrict__ g, const float* __restrict__ be,
    double* __restrict__ scsh) {
    __shared__ double red[256];
    const int t = threadIdx.x;
    const int c = t & 63, grp = t >> 6;
    double s = 0.0;
    for (int i = grp; i < nblocks; i += 4) s += part[(size_t)i * 64 + c];
    red[t] = s;
    __syncthreads();
    if (t < 64) red[t] = red[t] + red[64 + t] + red[128 + t] + red[192 + t];
    __syncthreads();
    if (t < 32) {
        double mean = red[t] * invcount;
        double var = red[32 + t] * invcount - mean * mean;
        double sc = (double)g[t] / sqrt(var + 1e-5);
        scsh[t] = sc;
        scsh[32 + t] = (double)be[t] - mean * sc;
    }
}

// ---------------------------------------------------------------------------
// K1: conv1 stats (fp32 conv, fp64 sums)
// ---------------------------------------------------------------------------
__global__ __launch_bounds__(256) void conv1_stats_kernel(
    const float* __restrict__ x, const float* __restrict__ w1t,
    double* __restrict__ part) {
    __shared__ float xs[3456];
    __shared__ float wt[864];
    __shared__ double red[4][2][32];
    const int n = blockIdx.x, t = threadIdx.x;
    const float* xin = x + (size_t)n * 3072;
    for (int i = t; i < 3072; i += 256) {
        int ci = i >> 10, rem = i & 1023;
        xs[ci * 1152 + (rem >> 5) * 36 + (rem & 31)] = xin[i];
    }
    for (int i = t; i < 384; i += 256) {
        int ci = i >> 7, rem = i & 127;
        xs[ci * 1152 + (rem >> 2) * 36 + 32 + (rem & 3)] = 0.f;
    }
    for (int i = t; i < 864; i += 256) wt[i] = w1t[i];
    __syncthreads();
    const int cg = t & 3, c0 = cg * 8;
    double sm[8] = {}, sq[8] = {};
    for (int task = t; task < 960; task += 256) {
        const int chunk = task >> 2;
        const int r = chunk >> 3, wc = (chunk & 7) * 4;
        float acc[4][8] = {};
        for (int ci = 0; ci < 3; ++ci) {
            float v[3][6];
#pragma unroll
            for (int rr = 0; rr < 3; ++rr) {
                const float* p = &xs[ci * 1152 + (r + rr) * 36 + wc];
                float4 a = *(const float4*)p;
                float2 b = *(const float2*)(p + 4);
                v[rr][0] = a.x; v[rr][1] = a.y; v[rr][2] = a.z; v[rr][3] = a.w;
                v[rr][4] = b.x; v[rr][5] = b.y;
            }
#pragma unroll
            for (int th = 0; th < 3; ++th)
#pragma unroll
            for (int tw = 0; tw < 3; ++tw) {
                const float* wp = &wt[(ci * 9 + th * 3 + tw) * 32 + c0];
                float4 wa = *(const float4*)wp;
                float4 wb = *(const float4*)(wp + 4);
                float w8[8] = {wa.x, wa.y, wa.z, wa.w, wb.x, wb.y, wb.z, wb.w};
#pragma unroll
                for (int j = 0; j < 4; ++j) {
                    float xv = v[th][j + tw];
#pragma unroll
                    for (int c = 0; c < 8; ++c) acc[j][c] += xv * w8[c];
                }
            }
        }
#pragma unroll
        for (int j = 0; j < 4; ++j) {
            if (wc + j < 30) {
#pragma unroll
                for (int c = 0; c < 8; ++c) {
                    double y = (double)acc[j][c];
                    sm[c] += y; sq[c] += y * y;
                }
            }
        }
    }
#pragma unroll
    for (int m = 4; m <= 32; m <<= 1)
#pragma unroll
        for (int c = 0; c < 8; ++c) {
            sm[c] += __shfl_xor(sm[c], m);
            sq[c] += __shfl_xor(sq[c], m);
        }
    const int wv = t >> 6, lane = t & 63;
    if (lane < 4) {
#pragma unroll
        for (int c = 0; c < 8; ++c) {
            red[wv][0][lane * 8 + c] = sm[c];
            red[wv][1][lane * 8 + c] = sq[c];
        }
    }
    __syncthreads();
    if (t < 64) {
        int which = t >> 5, ch = t & 31;
        part[(size_t)n * 64 + t] = red[0][which][ch] + red[1][which][ch] +
                                   red[2][which][ch] + red[3][which][ch];
    }
}

// ---------------------------------------------------------------------------
// K2: conv1 + BN(fp64) + relu + pool -> s1p [n][32][15][16]
// ---------------------------------------------------------------------------
__global__ __launch_bounds__(512) void conv1_apply_kernel(
    const float* __restrict__ x, const float* __restrict__ w1t,
    const double* __restrict__ scsh, float* __restrict__ s1p) {
    __shared__ float xs[3456];
    __shared__ float wt[864];
    __shared__ double bn[64];
    const int n = blockIdx.x, t = threadIdx.x;
    const float* xin = x + (size_t)n * 3072;
    for (int i = t; i < 3072; i += 512) {
        int ci = i >> 10, rem = i & 1023;
        xs[ci * 1152 + (rem >> 5) * 36 + (rem & 31)] = xin[i];
    }
    for (int i = t; i < 384; i += 512) {
        int ci = i >> 7, rem = i & 127;
        xs[ci * 1152 + (rem >> 2) * 36 + 32 + (rem & 3)] = 0.f;
    }
    for (int i = t; i < 864; i += 512) wt[i] = w1t[i];
    if (t < 64) bn[t] = scsh[t];
    __syncthreads();
    const bool act = t < 480;
    const int cg = t & 3, c0 = cg * 8;
    const int chunk = act ? (t >> 2) : 119;
    const int ph = chunk >> 3, pw0 = (chunk & 7) * 2;
    const int xr = 2 * ph, xw = 2 * pw0;
    float acc[2][4][8] = {};
    for (int ci = 0; ci < 3; ++ci) {
        float v[4][6];
#pragma unroll
        for (int rr = 0; rr < 4; ++rr) {
            const float* p = &xs[ci * 1152 + (xr + rr) * 36 + xw];
            float4 a = *(const float4*)p;
            float2 b = *(const float2*)(p + 4);
            v[rr][0] = a.x; v[rr][1] = a.y; v[rr][2] = a.z; v[rr][3] = a.w;
            v[rr][4] = b.x; v[rr][5] = b.y;
        }
#pragma unroll
        for (int th = 0; th < 3; ++th)
#pragma unroll
        for (int tw = 0; tw < 3; ++tw) {
            const float* wp = &wt[(ci * 9 + th * 3 + tw) * 32 + c0];
            float4 wa = *(const float4*)wp;
            float4 wb = *(const float4*)(wp + 4);
            float w8[8] = {wa.x, wa.y, wa.z, wa.w, wb.x, wb.y, wb.z, wb.w};
#pragma unroll
            for (int rr = 0; rr < 2; ++rr)
#pragma unroll
            for (int ww = 0; ww < 4; ++ww) {
                float xv = v[rr + th][ww + tw];
#pragma unroll
                for (int c = 0; c < 8; ++c) acc[rr][ww][c] += xv * w8[c];
            }
        }
    }
    if (act) {
#pragma unroll
        for (int c = 0; c < 8; ++c) {
            double s = bn[c0 + c], h = bn[32 + c0 + c];
            double p0 = 0.25 * (fmax((double)acc[0][0][c] * s + h, 0.0) +
                                fmax((double)acc[0][1][c] * s + h, 0.0) +
                                fmax((double)acc[1][0][c] * s + h, 0.0) +
                                fmax((double)acc[1][1][c] * s + h, 0.0));
            double p1 = 0.25 * (fmax((double)acc[0][2][c] * s + h, 0.0) +
                                fmax((double)acc[0][3][c] * s + h, 0.0) +
                                fmax((double)acc[1][2][c] * s + h, 0.0) +
                                fmax((double)acc[1][3][c] * s + h, 0.0));
            float p1s = (pw0 < 14) ? (float)p1 : 0.f;
            float* dst = s1p + (size_t)n * 7680 + (c0 + c) * 240 + ph * 16 + pw0;
            *(float2*)dst = make_float2((float)p0, p1s);
        }
    }
}

// ---------------------------------------------------------------------------
// K3: conv2 — fp32 9-MAC per-ci chains, fp64 flush per ci. fp64 stats.
// ---------------------------------------------------------------------------
__global__ __launch_bounds__(256) void conv2_kernel(
    const float* __restrict__ s1p, const float* __restrict__ w2t,
    float* __restrict__ s2c, double* __restrict__ part) {
    __shared__ float img[7684];
    __shared__ float wt[4608];
    __shared__ double red[4][2][32];
    const int n = blockIdx.x, t = threadIdx.x;
    {
        const float4* src = (const float4*)(s1p + (size_t)n * 7680);
        float4* d = (float4*)img;
        for (int i = t; i < 1920; i += 256) d[i] = src[i];
        if (t < 4) img[7680 + t] = 0.f;
    }
    const bool act = t < 208;
    const int cg = t & 3, c0 = cg * 8;
    const int chunk = act ? (t >> 2) : 51;
    const int oh = chunk >> 2, ow = (chunk & 3) * 4;
    double acc[4][8] = {};
    for (int phs = 0; phs < 2; ++phs) {
        __syncthreads();
        for (int i = t; i < 4608; i += 256) wt[i] = w2t[phs * 4608 + i];
        __syncthreads();
        for (int ci = 0; ci < 16; ++ci) {
            const int cig = phs * 16 + ci;
            float prt[4][8] = {};
#pragma unroll
            for (int th = 0; th < 3; ++th) {
                const float* ip = &img[cig * 240 + (oh + th) * 16 + ow];
                float4 a = *(const float4*)ip;
                float4 b = *(const float4*)(ip + 4);
                float v[8] = {a.x, a.y, a.z, a.w, b.x, b.y, b.z, b.w};
#pragma unroll
                for (int tw = 0; tw < 3; ++tw) {
                    const float* wp = &wt[(ci * 9 + th * 3 + tw) * 32 + c0];
                    float4 wa = *(const float4*)wp;
                    float4 wb = *(const float4*)(wp + 4);
                    float w8[8] = {wa.x, wa.y, wa.z, wa.w, wb.x, wb.y, wb.z, wb.w};
#pragma unroll
                    for (int j = 0; j < 4; ++j) {
                        float xv = v[j + tw];
#pragma unroll
                        for (int c = 0; c < 8; ++c) prt[j][c] += xv * w8[c];
                    }
                }
            }
#pragma unroll
            for (int j = 0; j < 4; ++j)
#pragma unroll
                for (int c = 0; c < 8; ++c) acc[j][c] += (double)prt[j][c];
        }
    }
#pragma unroll
    for (int j = 0; j < 4; ++j) {
        bool valid = act && (ow + j < 13);
        if (!valid) {
#pragma unroll
            for (int c = 0; c < 8; ++c) acc[j][c] = 0.0;
        }
    }
    if (act) {
#pragma unroll
        for (int c = 0; c < 8; ++c) {
            float* dst = s2c + (size_t)n * 6656 + (c0 + c) * 208 + oh * 16 + ow;
            *(float4*)dst = make_float4((float)acc[0][c], (float)acc[1][c],
                                        (float)acc[2][c], (float)acc[3][c]);
        }
    }
    double sm[8], sq[8];
#pragma unroll
    for (int c = 0; c < 8; ++c) {
        sm[c] = acc[0][c] + acc[1][c] + acc[2][c] + acc[3][c];
        sq[c] = acc[0][c] * acc[0][c] + acc[1][c] * acc[1][c] +
                acc[2][c] * acc[2][c] + acc[3][c] * acc[3][c];
    }
#pragma unroll
    for (int m = 4; m <= 32; m <<= 1)
#pragma unroll
        for (int c = 0; c < 8; ++c) {
            sm[c] += __shfl_xor(sm[c], m);
            sq[c] += __shfl_xor(sq[c], m);
        }
    const int wv = t >> 6, lane = t & 63;
    if (lane < 4) {
#pragma unroll
        for (int c = 0; c < 8; ++c) {
            red[wv][0][lane * 8 + c] = sm[c];
            red[wv][1][lane * 8 + c] = sq[c];
        }
    }
    __syncthreads();
    if (t < 64) {
        int which = t >> 5, ch = t & 31;
        part[(size_t)n * 64 + t] = red[0][which][ch] + red[1][which][ch] +
                                   red[2][which][ch] + red[3][which][ch];
    }
}

// ---------------------------------------------------------------------------
// K4: conv3 (fp64 acc) + fused BN2+relu+pool2 staging. 8 img/block.
// ---------------------------------------------------------------------------
__global__ __launch_bounds__(128) void conv3_kernel(
    const float* __restrict__ s2c, const float* __restrict__ w3t,
    const double* __restrict__ scsh2, float* __restrict__ s3c,
    double* __restrict__ part) {
    __shared__ float img[12288];
    __shared__ float wt[4608];
    __shared__ double red[2][2][32];
    const int n0 = blockIdx.x * 8, t = threadIdx.x;
    for (int i = t; i < 12288; i += 128) {
        int im = i / 1536, rem = i % 1536;
        int ci = rem / 48, r2 = rem % 48;
        int h = r2 >> 3, w = r2 & 7;
        float val = 0.f;
        if (w < 6) {
            const float* b = s2c + (size_t)(n0 + im) * 6656 + ci * 208 +
                             (2 * h) * 16 + 2 * w;
            double s = scsh2[ci], hh = scsh2[32 + ci];
            double a0 = fmax((double)b[0] * s + hh, 0.0);
            double a1 = fmax((double)b[1] * s + hh, 0.0);
            double a2 = fmax((double)b[16] * s + hh, 0.0);
            double a3 = fmax((double)b[17] * s + hh, 0.0);
            val = (float)(0.25 * (a0 + a1 + a2 + a3));
        }
        img[i] = val;
    }
    const int im = t >> 4, rem = t & 15;
    const int oh = rem >> 2, cg = rem & 3, c0 = cg * 8;
    double acc[4][8] = {};
    for (int phs = 0; phs < 2; ++phs) {
        __syncthreads();
        for (int i = t; i < 4608; i += 128) wt[i] = w3t[phs * 4608 + i];
        __syncthreads();
        for (int ci = 0; ci < 16; ++ci) {
            const int cig = phs * 16 + ci;
#pragma unroll
            for (int th = 0; th < 3; ++th) {
                const float* ip = &img[im * 1536 + cig * 48 + (oh + th) * 8];
                float4 a = *(const float4*)ip;
                float4 b = *(const float4*)(ip + 4);
                double v[8] = {a.x, a.y, a.z, a.w, b.x, b.y, b.z, b.w};
#pragma unroll
                for (int tw = 0; tw < 3; ++tw) {
                    const float* wp = &wt[(ci * 9 + th * 3 + tw) * 32 + c0];
                    float4 wa = *(const float4*)wp;
                    float4 wb = *(const float4*)(wp + 4);
                    double w8[8] = {wa.x, wa.y, wa.z, wa.w, wb.x, wb.y, wb.z, wb.w};
#pragma unroll
                    for (int j = 0; j < 4; ++j) {
                        double xv = v[j + tw];
#pragma unroll
                        for (int c = 0; c < 8; ++c) acc[j][c] += xv * w8[c];
                    }
                }
            }
        }
    }
#pragma unroll
    for (int c = 0; c < 8; ++c) {
        float* dst = s3c + (size_t)(n0 + im) * 512 + (c0 + c) * 16 + oh * 4;
        *(float4*)dst = make_float4((float)acc[0][c], (float)acc[1][c],
                                    (float)acc[2][c], (float)acc[3][c]);
    }
    double sm[8], sq[8];
#pragma unroll
    for (int c = 0; c < 8; ++c) {
        sm[c] = acc[0][c] + acc[1][c] + acc[2][c] + acc[3][c];
        sq[c] = acc[0][c] * acc[0][c] + acc[1][c] * acc[1][c] +
                acc[2][c] * acc[2][c] + acc[3][c] * acc[3][c];
    }
#pragma unroll
    for (int m = 4; m <= 32; m <<= 1)
#pragma unroll
        for (int c = 0; c < 8; ++c) {
            sm[c] += __shfl_xor(sm[c], m);
            sq[c] += __shfl_xor(sq[c], m);
        }
    const int wv = t >> 6, lane = t & 63;
    if (lane < 4) {
#pragma unroll
        for (int c = 0; c < 8; ++c) {
            red[wv][0][lane * 8 + c] = sm[c];
            red[wv][1][lane * 8 + c] = sq[c];
        }
    }
    __syncthreads();
    if (t < 64) {
        int which = t >> 5, ch = t & 31;
        part[(size_t)blockIdx.x * 64 + t] = red[0][which][ch] + red[1][which][ch];
    }
}

// ---------------------------------------------------------------------------
// K5: BN3(fp64)+relu+pool3 -> h0 NCHW-flat
// ---------------------------------------------------------------------------
__global__ void bn_pool3_h0(const float* __restrict__ s3c,
                            const double* __restrict__ scsh,
                            float* __restrict__ h0) {
    __shared__ double bn[64];
    const int t = threadIdx.x;
    if (t < 64) bn[t] = scsh[t];
    __syncthreads();
    const int idx = blockIdx.x * 256 + t;
    if (idx >= 262144) return;
    const int n = idx >> 7, rem = idx & 127;
    const int c = rem >> 2, q = rem & 3, ph = q >> 1, pw = q & 1;
    const float* b = s3c + (size_t)n * 512 + c * 16 + (2 * ph) * 4 + 2 * pw;
    const double s = bn[c], h = bn[32 + c];
    double a0 = fmax((double)b[0] * s + h, 0.0);
    double a1 = fmax((double)b[1] * s + h, 0.0);
    double a2 = fmax((double)b[4] * s + h, 0.0);
    double a3 = fmax((double)b[5] * s + h, 0.0);
    h0[idx] = (float)(0.25 * (a0 + a1 + a2 + a3));
}

// ---------------------------------------------------------------------------
// K6: beam level 0 (fp64)
// ---------------------------------------------------------------------------
__global__ void beam0_kernel(const float* __restrict__ h0, const float* __restrict__ Who,
                             const float* __restrict__ bho, double* __restrict__ scores,
                             int* __restrict__ op0, float* __restrict__ p0) {
    const int n = blockIdx.x, lane = threadIdx.x;
    const float* hr = h0 + (size_t)n * 128;
    double pt[4] = {};
    for (int i = lane; i < 128; i += 64) {
        double hv = hr[i];
        pt[0] += hv * (double)Who[i * 4 + 0];
        pt[1] += hv * (double)Who[i * 4 + 1];
        pt[2] += hv * (double)Who[i * 4 + 2];
        pt[3] += hv * (double)Who[i * 4 + 3];
    }
#pragma unroll
    for (int off = 32; off > 0; off >>= 1)
#pragma unroll
        for (int o = 0; o < 4; ++o) pt[o] += __shfl_down(pt[o], off);
    if (lane == 0) {
        double lg[4], e[4], probs[4], logp[4];
#pragma unroll
        for (int o = 0; o < 4; ++o) lg[o] = pt[o] + (double)bho[o];
        double m = fmax(fmax(lg[0], lg[1]), fmax(lg[2], lg[3]));
        double sum = 0.0;
#pragma unroll
        for (int o = 0; o < 4; ++o) { e[o] = exp(lg[o] - m); sum += e[o]; }
        double lse = log(sum);
#pragma unroll
        for (int o = 0; o < 4; ++o) {
            probs[o] = e[o] / sum;
            logp[o] = lg[o] - m - lse;
        }
        bool used[4] = {false, false, false, false};
        for (int slot = 0; slot < 4; ++slot) {
            int best = 0; double bv = -INFINITY;
            for (int o = 0; o < 4; ++o)
                if (!used[o] && logp[o] > bv) { bv = logp[o]; best = o; }
            used[best] = true;
            scores[n * 4 + slot] = bv;
            op0[n * 4 + slot] = best;
            p0[n * 4 + slot] = (float)probs[best];
        }
    }
}

// ---------------------------------------------------------------------------
// K8/K10: beam level >=1 (fp64)
// ---------------------------------------------------------------------------
__global__ void beam_level(const float* __restrict__ h, const float* __restrict__ Who,
                           const float* __restrict__ bho, double* __restrict__ scores,
                           int* __restrict__ opL, float* __restrict__ pL,
                           int* __restrict__ srcL) {
    __shared__ double logits[16], cand[16], pr[16];
    const int n = blockIdx.x, l = threadIdx.x;
    const int b = l >> 4, o = (l >> 2) & 3, qt = l & 3;
    const float* hr = h + ((size_t)n * 4 + b) * 128;
    double s = 0.0;
    for (int k = qt * 32; k < qt * 32 + 32; ++k)
        s += (double)hr[k] * (double)Who[k * 4 + o];
    s += __shfl_xor(s, 1);
    s += __shfl_xor(s, 2);
    if (qt == 0) logits[b * 4 + o] = s + (double)bho[o];
    __syncthreads();
    if (l < 4) {
        double lg[4];
#pragma unroll
        for (int o2 = 0; o2 < 4; ++o2) lg[o2] = logits[l * 4 + o2];
        double m = fmax(fmax(lg[0], lg[1]), fmax(lg[2], lg[3]));
        double e[4], sum = 0.0;
#pragma unroll
        for (int o2 = 0; o2 < 4; ++o2) { e[o2] = exp(lg[o2] - m); sum += e[o2]; }
        double lse = log(sum);
        double sb = scores[n * 4 + l];
#pragma unroll
        for (int o2 = 0; o2 < 4; ++o2) {
            pr[l * 4 + o2] = e[o2] / sum;
            cand[l * 4 + o2] = sb + (lg[o2] - m - lse);
        }
    }
    __syncthreads();
    if (l == 0) {
        bool used[16];
#pragma unroll
        for (int f = 0; f < 16; ++f) used[f] = false;
        double ns[4]; float np[4]; int nop[4], nsrc[4];
        for (int slot = 0; slot < 4; ++slot) {
            int best = 0; double bv = -INFINITY;
            for (int f = 0; f < 16; ++f)
                if (!used[f] && cand[f] > bv) { bv = cand[f]; best = f; }
            used[best] = true;
            ns[slot] = bv; nsrc[slot] = best >> 2; nop[slot] = best & 3;
            np[slot] = (float)pr[best];
        }
        for (int slot = 0; slot < 4; ++slot) {
            scores[n * 4 + slot] = ns[slot];
            opL[n * 4 + slot] = nop[slot];
            pL[n * 4 + slot] = np[slot];
            srcL[n * 4 + slot] = nsrc[slot];
        }
    }
}

// ---------------------------------------------------------------------------
// K7: h0_update — per-sample h0@Whh computed ONCE, broadcast over 4 beams.
// ---------------------------------------------------------------------------
__global__ __launch_bounds__(256) void h0_update(
    const float* __restrict__ h0, const int* __restrict__ op0,
    const float* __restrict__ Whh, const float* __restrict__ Eop,
    const float* __restrict__ bh, float* __restrict__ out) {
    __shared__ float A[256];
    const int s0 = blockIdx.x * 2, t = threadIdx.x;
    const int row = t >> 7, j = t & 127;
    const int s = s0 + row;
    A[t] = h0[(size_t)s * 128 + j];
    __syncthreads();
    double acc = 0.0;
#pragma unroll 8
    for (int k = 0; k < 128; ++k)
        acc += (double)A[row * 128 + k] * (double)Whh[k * 128 + j];
    double base = acc + (double)bh[j];
#pragma unroll
    for (int b = 0; b < 4; ++b) {
        int op = op0[s * 4 + b];
        out[(size_t)(s * 4 + b) * 128 + j] =
            (float)tanh(base + (double)Eop[op * 128 + j]);
    }
}

// ---------------------------------------------------------------------------
// K9: h_update (srcL gather)
// ---------------------------------------------------------------------------
__global__ __launch_bounds__(256) void h_update(
    const float* __restrict__ in, const int* __restrict__ srcL,
    const int* __restrict__ opL, const float* __restrict__ Whh,
    const float* __restrict__ Eop, const float* __restrict__ bh,
    float* __restrict__ out) {
    __shared__ float A[256];
    const int r0 = blockIdx.x * 2, t = threadIdx.x;
    const int row = t >> 7, j = t & 127;
    const int r = r0 + row;
    const float* src = in + (size_t)((r & ~3) + srcL[r]) * 128;
    A[t] = src[j];
    __syncthreads();
    double acc = 0.0;
#pragma unroll 8
    for (int k = 0; k < 128; ++k)
        acc += (double)A[row * 128 + k] * (double)Whh[k * 128 + j];
    out[(size_t)r * 128 + j] =
        (float)tanh(acc + (double)Eop[opL[r] * 128 + j] + (double)bh[j]);
}

// ---------------------------------------------------------------------------
// K11: sort_ops — single block, deterministic counting sort of rows by op
// ---------------------------------------------------------------------------
__global__ __launch_bounds__(256) void sort_ops(
    const int* __restrict__ op0, const int* __restrict__ op1,
    const int* __restrict__ op2, int* __restrict__ perm,
    int* __restrict__ blkop, int* __restrict__ blkstart,
    int* __restrict__ blkcnt) {
    __shared__ int cnt[256][4];
    __shared__ int tot[4];
    __shared__ int base[4];
    const int t = threadIdx.x;
    for (int L = 0; L < 3; ++L) {
        const int* ops = (L == 0) ? op0 : (L == 1) ? op1 : op2;
        int c[4] = {0, 0, 0, 0};
        for (int i = 0; i < 32; ++i) c[ops[t * 32 + i]]++;
#pragma unroll
        for (int b = 0; b < 4; ++b) cnt[t][b] = c[b];
        __syncthreads();
        if (t < 4) {
            int s = 0;
            for (int u = 0; u < 256; ++u) { int v = cnt[u][t]; cnt[u][t] = s; s += v; }
            tot[t] = s;
        }
        __syncthreads();
        if (t == 0) {
            base[0] = 0;
            for (int b = 1; b < 4; ++b) base[b] = base[b - 1] + tot[b - 1];
        }
        __syncthreads();
        int off[4];
#pragma unroll
        for (int b = 0; b < 4; ++b) off[b] = cnt[t][b];
        for (int i = 0; i < 32; ++i) {
            int r = t * 32 + i, o = ops[r];
            perm[L * 8192 + base[o] + off[o]] = r;
            off[o]++;
        }
        if (t == 0) {
            int nb = 0;
            for (int o = 0; o < 4; ++o) {
                int cbin = tot[o], gb = base[o];
                for (int s = 0; s < cbin; s += 32) {
                    blkop[L * 272 + nb] = o;
                    blkstart[L * 272 + nb] = L * 8192 + gb + s;
                    blkcnt[L * 272 + nb] = (cbin - s < 32) ? (cbin - s) : 32;
                    nb++;
                }
            }
            for (; nb < 272; ++nb) blkop[L * 272 + nb] = -1;
        }
        __syncthreads();
    }
}

// ---------------------------------------------------------------------------
// K12/K13: dispatch_sorted — 32 same-op rows/block, expert weights in LDS.
// [R6 FIX] As staging decomposition: row = i>>5, c4 = i&31 (32 rows x 32 f4).
// ---------------------------------------------------------------------------
__global__ __launch_bounds__(256) void dispatch_sorted(
    const float* __restrict__ in, int mode, const int* __restrict__ perm,
    const int* __restrict__ blkop, const int* __restrict__ blkstart,
    const int* __restrict__ blkcnt, const float* __restrict__ pL,
    const float* __restrict__ expw, const float* __restrict__ expb,
    float* __restrict__ out) {
    __shared__ float As[32][128];
    __shared__ float Ws[64][128];
    __shared__ int rowid[32];
    __shared__ float rowp[32];
    const int b = blockIdx.x, t = threadIdx.x;
    const int op = blkop[b];
    if (op < 0) return;
    const int start = blkstart[b], cntv = blkcnt[b];
    if (t < 32) {
        int r = (t < cntv) ? perm[start + t] : -1;
        rowid[t] = r;
        rowp[t] = (r >= 0) ? pL[r] : 0.f;
    }
    __syncthreads();
    for (int i = t; i < 1024; i += 256) {
        int row = i >> 5, c4 = i & 31;          // [R6 FIX]
        int r = rowid[row];
        float4 v = make_float4(0.f, 0.f, 0.f, 0.f);
        if (r >= 0) {
            const float* src = (mode == 0) ? in + (size_t)(r >> 2) * 128
                                           : in + (size_t)r * 128;
            v = *(const float4*)(src + c4 * 4);
        }
        *(float4*)&As[row][c4 * 4] = v;
    }
    const int tr = (t >> 5) * 4, tc = (t & 31) * 4;
    float res[4][4];
    if (op < 3) {
        const float* W = expw + (size_t)op * 16384;
        float acc[4][4] = {};
        for (int ph = 0; ph < 2; ++ph) {
            __syncthreads();
            for (int i = t; i < 2048; i += 256)
                ((float4*)Ws)[i] = ((const float4*)(W + ph * 8192))[i];
            __syncthreads();
            for (int k = 0; k < 64; ++k) {
                float a0 = As[tr + 0][ph * 64 + k];
                float a1 = As[tr + 1][ph * 64 + k];
                float a2 = As[tr + 2][ph * 64 + k];
                float a3 = As[tr + 3][ph * 64 + k];
                float4 w = *(const float4*)&Ws[k][tc];
                acc[0][0] += a0 * w.x; acc[0][1] += a0 * w.y;
                acc[0][2] += a0 * w.z; acc[0][3] += a0 * w.w;
                acc[1][0] += a1 * w.x; acc[1][1] += a1 * w.y;
                acc[1][2] += a1 * w.z; acc[1][3] += a1 * w.w;
                acc[2][0] += a2 * w.x; acc[2][1] += a2 * w.y;
                acc[2][2] += a2 * w.z; acc[2][3] += a2 * w.w;
                acc[3][0] += a3 * w.x; acc[3][1] += a3 * w.y;
                acc[3][2] += a3 * w.z; acc[3][3] += a3 * w.w;
            }
        }
        float4 eb = *(const float4*)&expb[op * 128 + tc];
#pragma unroll
        for (int i = 0; i < 4; ++i) {
            float p = rowp[tr + i];
            res[i][0] = fmaxf((acc[i][0] + eb.x) * p, 0.f);
            res[i][1] = fmaxf((acc[i][1] + eb.y) * p, 0.f);
            res[i][2] = fmaxf((acc[i][2] + eb.z) * p, 0.f);
            res[i][3] = fmaxf((acc[i][3] + eb.w) * p, 0.f);
        }
    } else {
        __syncthreads();
#pragma unroll
        for (int i = 0; i < 4; ++i) {
            float p = rowp[tr + i];
#pragma unroll
            for (int jj = 0; jj < 4; ++jj)
                res[i][jj] = fmaxf(As[tr + i][tc + jj] * p, 0.f);
        }
    }
#pragma unroll
    for (int i = 0; i < 4; ++i) {
        int r = rowid[tr + i];
        if (r >= 0)
            *(float4*)(out + (size_t)r * 128 + tc) =
                make_float4(res[i][0], res[i][1], res[i][2], res[i][3]);
    }
}

// ---------------------------------------------------------------------------
// K14: dispatch round 3 with fused final head (8192 x 10 -> d_out)
// [R6 FIX] same As staging decomposition fix.
// ---------------------------------------------------------------------------
__global__ __launch_bounds__(256) void dispatch_sorted_final(
    const float* __restrict__ in, const int* __restrict__ perm,
    const int* __restrict__ blkop, const int* __restrict__ blkstart,
    const int* __restrict__ blkcnt, const float* __restrict__ pL,
    const float* __restrict__ expw, const float* __restrict__ expb,
    const float* __restrict__ ow, const float* __restrict__ ob,
    float* __restrict__ dout) {
    __shared__ float As[32][128];
    __shared__ float Ws[64][128];
    __shared__ int rowid[32];
    __shared__ float rowp[32];
    const int b = blockIdx.x, t = threadIdx.x;
    const int op = blkop[b];
    if (op < 0) return;
    const int start = blkstart[b], cntv = blkcnt[b];
    if (t < 32) {
        int r = (t < cntv) ? perm[start + t] : -1;
        rowid[t] = r;
        rowp[t] = (r >= 0) ? pL[r] : 0.f;
    }
    __syncthreads();
    for (int i = t; i < 1024; i += 256) {
        int row = i >> 5, c4 = i & 31;          // [R6 FIX]
        int r = rowid[row];
        float4 v = make_float4(0.f, 0.f, 0.f, 0.f);
        if (r >= 0) v = *(const float4*)(in + (size_t)r * 128 + c4 * 4);
        *(float4*)&As[row][c4 * 4] = v;
    }
    const int tr = (t >> 5) * 4, tc = (t & 31) * 4;
    float res[4][4];
    if (op < 3) {
        const float* W = expw + (size_t)op * 16384;
        float acc[4][4] = {};
        for (int ph = 0; ph < 2; ++ph) {
            __syncthreads();
            for (int i = t; i < 2048; i += 256)
                ((float4*)Ws)[i] = ((const float4*)(W + ph * 8192))[i];
            __syncthreads();
            for (int k = 0; k < 64; ++k) {
                float a0 = As[tr + 0][ph * 64 + k];
                float a1 = As[tr + 1][ph * 64 + k];
                float a2 = As[tr + 2][ph * 64 + k];
                float a3 = As[tr + 3][ph * 64 + k];
                float4 w = *(const float4*)&Ws[k][tc];
                acc[0][0] += a0 * w.x; acc[0][1] += a0 * w.y;
                acc[0][2] += a0 * w.z; acc[0][3] += a0 * w.w;
                acc[1][0] += a1 * w.x; acc[1][1] += a1 * w.y;
                acc[1][2] += a1 * w.z; acc[1][3] += a1 * w.w;
                acc[2][0] += a2 * w.x; acc[2][1] += a2 * w.y;
                acc[2][2] += a2 * w.z; acc[2][3] += a2 * w.w;
                acc[3][0] += a3 * w.x; acc[3][1] += a3 * w.y;
                acc[3][2] += a3 * w.z; acc[3][3] += a3 * w.w;
            }
        }
        float4 eb = *(const float4*)&expb[op * 128 + tc];
#pragma unroll
        for (int i = 0; i < 4; ++i) {
            float p = rowp[tr + i];
            res[i][0] = fmaxf((acc[i][0] + eb.x) * p, 0.f);
            res[i][1] = fmaxf((acc[i][1] + eb.y) * p, 0.f);
            res[i][2] = fmaxf((acc[i][2] + eb.z) * p, 0.f);
            res[i][3] = fmaxf((acc[i][3] + eb.w) * p, 0.f);
        }
    } else {
        __syncthreads();
#pragma unroll
        for (int i = 0; i < 4; ++i) {
            float p = rowp[tr + i];
#pragma unroll
            for (int jj = 0; jj < 4; ++jj)
                res[i][jj] = fmaxf(As[tr + i][tc + jj] * p, 0.f);
        }
    }
    __syncthreads();   // all As reads done; safe to overwrite with results
#pragma unroll
    for (int i = 0; i < 4; ++i)
        *(float4*)&As[tr + i][tc] =
            make_float4(res[i][0], res[i][1], res[i][2], res[i][3]);
    __syncthreads();
    for (int u = t; u < 320; u += 256) {
        int row = u / 10, o = u % 10;
        int r = rowid[row];
        if (r < 0) continue;
        float acc2 = ob[o];
#pragma unroll 8
        for (int k = 0; k < 128; ++k) acc2 += As[row][k] * ow[k * 10 + o];
        dout[(size_t)r * 10 + o] = acc2;
    }
}

// ===========================================================================
extern "C" void kernel_launch(void* const* d_in, const int* in_sizes, int n_in,
                              void* d_out, int out_size, void* d_ws, size_t ws_size,
                              hipStream_t stream) {
    const float* x    = (const float*)d_in[0];
    const float* cw1  = (const float*)d_in[1];
    const float* g1   = (const float*)d_in[3];
    const float* be1  = (const float*)d_in[4];
    const float* cw2  = (const float*)d_in[5];
    const float* g2   = (const float*)d_in[7];
    const float* be2  = (const float*)d_in[8];
    const float* cw3  = (const float*)d_in[9];
    const float* g3   = (const float*)d_in[11];
    const float* be3  = (const float*)d_in[12];
    const float* Whh  = (const float*)d_in[13];
    const float* bh   = (const float*)d_in[14];
    const float* Eop  = (const float*)d_in[15];
    const float* Who  = (const float*)d_in[16];
    const float* bho  = (const float*)d_in[17];
    const float* expw = (const float*)d_in[18];
    const float* expb = (const float*)d_in[19];
    const float* outw = (const float*)d_in[20];
    const float* outb = (const float*)d_in[21];
    float*  ws    = (float*)d_ws;
    float*  out   = (float*)d_out;
    double* scsh  = (double*)(ws + O_SC);
    double* part  = (double*)(ws + O_PART);
    double* score = (double*)(ws + O_SCORES);
    int* perm   = (int*)(ws + O_PERM);
    int* blkop  = (int*)(ws + O_BLKOP);
    int* blkst  = (int*)(ws + O_BLKST);
    int* blkct  = (int*)(ws + O_BLKCT);

    prep_w<<<36, 256, 0, stream>>>(cw1, cw2, cw3, ws + O_W1T, ws + O_W2T, ws + O_W3T);

    // ---- backbone ----
    conv1_stats_kernel<<<2048, 256, 0, stream>>>(x, ws + O_W1T, part);
    finalize_stats<<<1, 256, 0, stream>>>(part, 2048, 1.0 / 1843200.0, g1, be1, scsh);
    conv1_apply_kernel<<<2048, 512, 0, stream>>>(x, ws + O_W1T, scsh, ws + O_S1P);
    conv2_kernel<<<2048, 256, 0, stream>>>(ws + O_S1P, ws + O_W2T, ws + O_S2C, part);
    finalize_stats<<<1, 256, 0, stream>>>(part, 2048, 1.0 / 346112.0, g2, be2, scsh + 64);
    conv3_kernel<<<256, 128, 0, stream>>>(ws + O_S2C, ws + O_W3T, scsh + 64,
                                          ws + O_S3C, part);
    finalize_stats<<<1, 256, 0, stream>>>(part, 256, 1.0 / 32768.0, g3, be3, scsh + 128);
    bn_pool3_h0<<<1024, 256, 0, stream>>>(ws + O_S3C, scsh + 128, ws + O_H0);

    // ---- beam search ----
    beam0_kernel<<<2048, 64, 0, stream>>>(ws + O_H0, Who, bho, score,
                                          (int*)(ws + O_OP0), ws + O_P0);
    h0_update<<<1024, 256, 0, stream>>>(ws + O_H0, (int*)(ws + O_OP0),
                                        Whh, Eop, bh, ws + O_H);
    beam_level<<<2048, 64, 0, stream>>>(ws + O_H, Who, bho, score,
                                        (int*)(ws + O_OP1), ws + O_P1,
                                        (int*)(ws + O_SRC1));
    h_update<<<4096, 256, 0, stream>>>(ws + O_H, (int*)(ws + O_SRC1),
                                       (int*)(ws + O_OP1), Whh, Eop, bh, ws + O_H2);
    beam_level<<<2048, 64, 0, stream>>>(ws + O_H2, Who, bho, score,
                                        (int*)(ws + O_OP2), ws + O_P2,
                                        (int*)(ws + O_SRC2));

    // ---- sorted expert dispatch (3 rounds; round 3 fuses the head) ----
    sort_ops<<<1, 256, 0, stream>>>((int*)(ws + O_OP0), (int*)(ws + O_OP1),
                                    (int*)(ws + O_OP2), perm, blkop, blkst, blkct);
    dispatch_sorted<<<260, 256, 0, stream>>>(ws + O_H0, 0, perm, blkop, blkst,
                                             blkct, ws + O_P0, expw, expb,
                                             ws + O_HIDA);
    dispatch_sorted<<<260, 256, 0, stream>>>(ws + O_HIDA, 1, perm, blkop + 272,
                                             blkst + 272, blkct + 272, ws + O_P1,
                                             expw, expb, ws + O_HIDB);
    dispatch_sorted_final<<<260, 256, 0, stream>>>(ws + O_HIDB, perm, blkop + 544,
                                                   blkst + 544, blkct + 544,
                                                   ws + O_P2, expw, expb,
                                                   outw, outb, out);
}

// Round 7
// 887.718 us; speedup vs baseline: 1.0915x; 1.0517x over previous
//
#include <hip/hip_runtime.h>
#include <cstdint>

// ============================================================================
// Supernetwork: conv-bn-relu-pool x3 backbone -> beam search -> expert dispatch
// R7: (a) conv2 ci-phased img staging (LDS 51.7->36KB => 4 blocks/CU) and
// fp64 flush every 2 ci (18-MAC fp32 chains); (b) conv3 fp32 chains + fp32
// BN2 staging + 2px threads (1024 waves); (c) conv1_apply BN in fp32.
// Decision-critical ladder stays fp64: BN stats, beam logits/scores, h.
// ============================================================================

// ---- ws layout (floats; doubles occupy 2 slots, all double offsets even) ----
static constexpr size_t O_SC    = 0;        // 192 doubles = 384 f
static constexpr size_t O_W1T   = 512;      // 864 f
static constexpr size_t O_W2T   = 1408;     // 9216 f
static constexpr size_t O_W3T   = 10624;    // 9216 f
static constexpr size_t O_SCORES= 19840;    // 8192 doubles
static constexpr size_t O_P0    = 36224;    // 8192 f each
static constexpr size_t O_P1    = 44416;
static constexpr size_t O_P2    = 52608;
static constexpr size_t O_OP0   = 60800;    // int32
static constexpr size_t O_OP1   = 68992;
static constexpr size_t O_OP2   = 77184;
static constexpr size_t O_SRC1  = 85376;
static constexpr size_t O_SRC2  = 93568;
static constexpr size_t O_H0    = 101760;   // 2048*128
static constexpr size_t O_H     = 363904;   // 8192*128 (beam h / partials / HIDB)
static constexpr size_t O_H2    = 1412480;  // 8192*128 (beam h2 / sort tables)
static constexpr size_t O_PART  = O_H;
static constexpr size_t O_S1P   = 2461056;  // 2048*7680; dead after conv2
static constexpr size_t O_S3C   = O_S1P;    // 2048*512
static constexpr size_t O_S2C   = 18189696; // 2048*6656; dead after conv3
static constexpr size_t O_HIDA  = O_S2C;
static constexpr size_t O_HIDB  = O_H;
static constexpr size_t O_PERM  = O_H2;             // 3*8192 int
static constexpr size_t O_BLKOP = O_H2 + 24576;     // 3*272 int
static constexpr size_t O_BLKST = O_H2 + 25392;     // 3*272 int
static constexpr size_t O_BLKCT = O_H2 + 26208;     // 3*272 int

// ---------------------------------------------------------------------------
// K0: weights -> k-major [(ci*9+tap)*32 + co]
// ---------------------------------------------------------------------------
__global__ void prep_w(const float* __restrict__ w1, const float* __restrict__ w2,
                       const float* __restrict__ w3, float* __restrict__ w1t,
                       float* __restrict__ w2t, float* __restrict__ w3t) {
    int t = blockIdx.x * 256 + threadIdx.x;
    if (t < 864) {
        int co = t / 27, k = t % 27;
        w1t[k * 32 + co] = w1[t];
    }
    if (t < 9216) {
        int co = t / 288, k = t % 288;
        w2t[k * 32 + co] = w2[t];
        w3t[k * 32 + co] = w3[t];
    }
}

// ---------------------------------------------------------------------------
// finalize_stats (fp64)
// ---------------------------------------------------------------------------
__global__ __launch_bounds__(256) void finalize_stats(
    const double* __restrict__ part, int nblocks, double invcount,
    const float* __restrict__ g, const float* __restrict__ be,
    double* __restrict__ scsh) {
    __shared__ double red[256];
    const int t = threadIdx.x;
    const int c = t & 63, grp = t >> 6;
    double s = 0.0;
    for (int i = grp; i < nblocks; i += 4) s += part[(size_t)i * 64 + c];
    red[t] = s;
    __syncthreads();
    if (t < 64) red[t] = red[t] + red[64 + t] + red[128 + t] + red[192 + t];
    __syncthreads();
    if (t < 32) {
        double mean = red[t] * invcount;
        double var = red[32 + t] * invcount - mean * mean;
        double sc = (double)g[t] / sqrt(var + 1e-5);
        scsh[t] = sc;
        scsh[32 + t] = (double)be[t] - mean * sc;
    }
}

// ---------------------------------------------------------------------------
// K1: conv1 stats (fp32 conv, fp64 sums) — unchanged (R4-proven)
// ---------------------------------------------------------------------------
__global__ __launch_bounds__(256) void conv1_stats_kernel(
    const float* __restrict__ x, const float* __restrict__ w1t,
    double* __restrict__ part) {
    __shared__ float xs[3456];
    __shared__ float wt[864];
    __shared__ double red[4][2][32];
    const int n = blockIdx.x, t = threadIdx.x;
    const float* xin = x + (size_t)n * 3072;
    for (int i = t; i < 3072; i += 256) {
        int ci = i >> 10, rem = i & 1023;
        xs[ci * 1152 + (rem >> 5) * 36 + (rem & 31)] = xin[i];
    }
    for (int i = t; i < 384; i += 256) {
        int ci = i >> 7, rem = i & 127;
        xs[ci * 1152 + (rem >> 2) * 36 + 32 + (rem & 3)] = 0.f;
    }
    for (int i = t; i < 864; i += 256) wt[i] = w1t[i];
    __syncthreads();
    const int cg = t & 3, c0 = cg * 8;
    double sm[8] = {}, sq[8] = {};
    for (int task = t; task < 960; task += 256) {
        const int chunk = task >> 2;
        const int r = chunk >> 3, wc = (chunk & 7) * 4;
        float acc[4][8] = {};
        for (int ci = 0; ci < 3; ++ci) {
            float v[3][6];
#pragma unroll
            for (int rr = 0; rr < 3; ++rr) {
                const float* p = &xs[ci * 1152 + (r + rr) * 36 + wc];
                float4 a = *(const float4*)p;
                float2 b = *(const float2*)(p + 4);
                v[rr][0] = a.x; v[rr][1] = a.y; v[rr][2] = a.z; v[rr][3] = a.w;
                v[rr][4] = b.x; v[rr][5] = b.y;
            }
#pragma unroll
            for (int th = 0; th < 3; ++th)
#pragma unroll
            for (int tw = 0; tw < 3; ++tw) {
                const float* wp = &wt[(ci * 9 + th * 3 + tw) * 32 + c0];
                float4 wa = *(const float4*)wp;
                float4 wb = *(const float4*)(wp + 4);
                float w8[8] = {wa.x, wa.y, wa.z, wa.w, wb.x, wb.y, wb.z, wb.w};
#pragma unroll
                for (int j = 0; j < 4; ++j) {
                    float xv = v[th][j + tw];
#pragma unroll
                    for (int c = 0; c < 8; ++c) acc[j][c] += xv * w8[c];
                }
            }
        }
#pragma unroll
        for (int j = 0; j < 4; ++j) {
            if (wc + j < 30) {
#pragma unroll
                for (int c = 0; c < 8; ++c) {
                    double y = (double)acc[j][c];
                    sm[c] += y; sq[c] += y * y;
                }
            }
        }
    }
#pragma unroll
    for (int m = 4; m <= 32; m <<= 1)
#pragma unroll
        for (int c = 0; c < 8; ++c) {
            sm[c] += __shfl_xor(sm[c], m);
            sq[c] += __shfl_xor(sq[c], m);
        }
    const int wv = t >> 6, lane = t & 63;
    if (lane < 4) {
#pragma unroll
        for (int c = 0; c < 8; ++c) {
            red[wv][0][lane * 8 + c] = sm[c];
            red[wv][1][lane * 8 + c] = sq[c];
        }
    }
    __syncthreads();
    if (t < 64) {
        int which = t >> 5, ch = t & 31;
        part[(size_t)n * 64 + t] = red[0][which][ch] + red[1][which][ch] +
                                   red[2][which][ch] + red[3][which][ch];
    }
}

// ---------------------------------------------------------------------------
// K2: conv1 + BN(fp32 apply, fp64-derived scales) + relu + pool -> s1p
// ---------------------------------------------------------------------------
__global__ __launch_bounds__(512) void conv1_apply_kernel(
    const float* __restrict__ x, const float* __restrict__ w1t,
    const double* __restrict__ scsh, float* __restrict__ s1p) {
    __shared__ float xs[3456];
    __shared__ float wt[864];
    __shared__ float bn[64];
    const int n = blockIdx.x, t = threadIdx.x;
    const float* xin = x + (size_t)n * 3072;
    for (int i = t; i < 3072; i += 512) {
        int ci = i >> 10, rem = i & 1023;
        xs[ci * 1152 + (rem >> 5) * 36 + (rem & 31)] = xin[i];
    }
    for (int i = t; i < 384; i += 512) {
        int ci = i >> 7, rem = i & 127;
        xs[ci * 1152 + (rem >> 2) * 36 + 32 + (rem & 3)] = 0.f;
    }
    for (int i = t; i < 864; i += 512) wt[i] = w1t[i];
    if (t < 64) bn[t] = (float)scsh[t];
    __syncthreads();
    const bool act = t < 480;
    const int cg = t & 3, c0 = cg * 8;
    const int chunk = act ? (t >> 2) : 119;
    const int ph = chunk >> 3, pw0 = (chunk & 7) * 2;
    const int xr = 2 * ph, xw = 2 * pw0;
    float acc[2][4][8] = {};
    for (int ci = 0; ci < 3; ++ci) {
        float v[4][6];
#pragma unroll
        for (int rr = 0; rr < 4; ++rr) {
            const float* p = &xs[ci * 1152 + (xr + rr) * 36 + xw];
            float4 a = *(const float4*)p;
            float2 b = *(const float2*)(p + 4);
            v[rr][0] = a.x; v[rr][1] = a.y; v[rr][2] = a.z; v[rr][3] = a.w;
            v[rr][4] = b.x; v[rr][5] = b.y;
        }
#pragma unroll
        for (int th = 0; th < 3; ++th)
#pragma unroll
        for (int tw = 0; tw < 3; ++tw) {
            const float* wp = &wt[(ci * 9 + th * 3 + tw) * 32 + c0];
            float4 wa = *(const float4*)wp;
            float4 wb = *(const float4*)(wp + 4);
            float w8[8] = {wa.x, wa.y, wa.z, wa.w, wb.x, wb.y, wb.z, wb.w};
#pragma unroll
            for (int rr = 0; rr < 2; ++rr)
#pragma unroll
            for (int ww = 0; ww < 4; ++ww) {
                float xv = v[rr + th][ww + tw];
#pragma unroll
                for (int c = 0; c < 8; ++c) acc[rr][ww][c] += xv * w8[c];
            }
        }
    }
    if (act) {
#pragma unroll
        for (int c = 0; c < 8; ++c) {
            float s = bn[c0 + c], h = bn[32 + c0 + c];
            float p0 = 0.25f * (fmaxf(fmaf(acc[0][0][c], s, h), 0.f) +
                                fmaxf(fmaf(acc[0][1][c], s, h), 0.f) +
                                fmaxf(fmaf(acc[1][0][c], s, h), 0.f) +
                                fmaxf(fmaf(acc[1][1][c], s, h), 0.f));
            float p1 = 0.25f * (fmaxf(fmaf(acc[0][2][c], s, h), 0.f) +
                                fmaxf(fmaf(acc[0][3][c], s, h), 0.f) +
                                fmaxf(fmaf(acc[1][2][c], s, h), 0.f) +
                                fmaxf(fmaf(acc[1][3][c], s, h), 0.f));
            float p1s = (pw0 < 14) ? p1 : 0.f;
            float* dst = s1p + (size_t)n * 7680 + (c0 + c) * 240 + ph * 16 + pw0;
            *(float2*)dst = make_float2(p0, p1s);
        }
    }
}

// ---------------------------------------------------------------------------
// K3: conv2 — ci-phased staging (img half + wt half per phase; LDS ~36KB =>
// 4 blocks/CU) + fp32 chains flushed to fp64 every 2 ci. fp64 stats.
// ---------------------------------------------------------------------------
__global__ __launch_bounds__(256) void conv2_kernel(
    const float* __restrict__ s1p, const float* __restrict__ w2t,
    float* __restrict__ s2c, double* __restrict__ part) {
    __shared__ float img[3844];   // 16 ci x 15 x 16 + 4 guard
    __shared__ float wt[4608];
    __shared__ double red[4][2][32];
    const int n = blockIdx.x, t = threadIdx.x;
    const bool act = t < 208;
    const int cg = t & 3, c0 = cg * 8;
    const int chunk = act ? (t >> 2) : 51;
    const int oh = chunk >> 2, ow = (chunk & 3) * 4;
    double acc[4][8] = {};
    for (int phs = 0; phs < 2; ++phs) {
        __syncthreads();
        {
            const float4* src = (const float4*)(s1p + (size_t)n * 7680 + phs * 3840);
            float4* d = (float4*)img;
            for (int i = t; i < 960; i += 256) d[i] = src[i];
            if (t < 4) img[3840 + t] = 0.f;
            for (int i = t; i < 4608; i += 256) wt[i] = w2t[phs * 4608 + i];
        }
        __syncthreads();
        for (int cp = 0; cp < 8; ++cp) {          // 8 pairs of ci
            float prt[4][8] = {};
#pragma unroll
            for (int ch2 = 0; ch2 < 2; ++ch2) {
                const int ci = cp * 2 + ch2;      // local ci in [0,16)
#pragma unroll
                for (int th = 0; th < 3; ++th) {
                    const float* ip = &img[ci * 240 + (oh + th) * 16 + ow];
                    float4 a = *(const float4*)ip;
                    float4 b = *(const float4*)(ip + 4);
                    float v[8] = {a.x, a.y, a.z, a.w, b.x, b.y, b.z, b.w};
#pragma unroll
                    for (int tw = 0; tw < 3; ++tw) {
                        const float* wp = &wt[(ci * 9 + th * 3 + tw) * 32 + c0];
                        float4 wa = *(const float4*)wp;
                        float4 wb = *(const float4*)(wp + 4);
                        float w8[8] = {wa.x, wa.y, wa.z, wa.w,
                                       wb.x, wb.y, wb.z, wb.w};
#pragma unroll
                        for (int j = 0; j < 4; ++j) {
                            float xv = v[j + tw];
#pragma unroll
                            for (int c = 0; c < 8; ++c) prt[j][c] += xv * w8[c];
                        }
                    }
                }
            }
#pragma unroll
            for (int j = 0; j < 4; ++j)
#pragma unroll
                for (int c = 0; c < 8; ++c) acc[j][c] += (double)prt[j][c];
        }
    }
#pragma unroll
    for (int j = 0; j < 4; ++j) {
        bool valid = act && (ow + j < 13);
        if (!valid) {
#pragma unroll
            for (int c = 0; c < 8; ++c) acc[j][c] = 0.0;
        }
    }
    if (act) {
#pragma unroll
        for (int c = 0; c < 8; ++c) {
            float* dst = s2c + (size_t)n * 6656 + (c0 + c) * 208 + oh * 16 + ow;
            *(float4*)dst = make_float4((float)acc[0][c], (float)acc[1][c],
                                        (float)acc[2][c], (float)acc[3][c]);
        }
    }
    double sm[8], sq[8];
#pragma unroll
    for (int c = 0; c < 8; ++c) {
        sm[c] = acc[0][c] + acc[1][c] + acc[2][c] + acc[3][c];
        sq[c] = acc[0][c] * acc[0][c] + acc[1][c] * acc[1][c] +
                acc[2][c] * acc[2][c] + acc[3][c] * acc[3][c];
    }
#pragma unroll
    for (int m = 4; m <= 32; m <<= 1)
#pragma unroll
        for (int c = 0; c < 8; ++c) {
            sm[c] += __shfl_xor(sm[c], m);
            sq[c] += __shfl_xor(sq[c], m);
        }
    const int wv = t >> 6, lane = t & 63;
    if (lane < 4) {
#pragma unroll
        for (int c = 0; c < 8; ++c) {
            red[wv][0][lane * 8 + c] = sm[c];
            red[wv][1][lane * 8 + c] = sq[c];
        }
    }
    __syncthreads();
    if (t < 64) {
        int which = t >> 5, ch = t & 31;
        part[(size_t)n * 64 + t] = red[0][which][ch] + red[1][which][ch] +
                                   red[2][which][ch] + red[3][which][ch];
    }
}

// ---------------------------------------------------------------------------
// K4: conv3 — fp32 chains (flush fp64 every 2 ci), fp32 BN2 staging.
// 8 img/block, 256 threads (thread = 2px x 8ch => 1024 waves total).
// ---------------------------------------------------------------------------
__global__ __launch_bounds__(256) void conv3_kernel(
    const float* __restrict__ s2c, const float* __restrict__ w3t,
    const double* __restrict__ scsh2, float* __restrict__ s3c,
    double* __restrict__ part) {
    __shared__ float img[12288];  // 8 img x 32 ci x 6 x 8 (cols 6,7 = 0)
    __shared__ float wt[4608];
    __shared__ float bns[64];
    __shared__ double red[4][2][32];
    const int n0 = blockIdx.x * 8, t = threadIdx.x;
    if (t < 64) bns[t] = (float)scsh2[t];
    __syncthreads();
    for (int i = t; i < 12288; i += 256) {
        int im = i / 1536, rem = i % 1536;
        int ci = rem / 48, r2 = rem % 48;
        int h = r2 >> 3, w = r2 & 7;
        float val = 0.f;
        if (w < 6) {
            const float* b = s2c + (size_t)(n0 + im) * 6656 + ci * 208 +
                             (2 * h) * 16 + 2 * w;
            float s = bns[ci], hh = bns[32 + ci];
            float a0 = fmaxf(fmaf(b[0], s, hh), 0.f);
            float a1 = fmaxf(fmaf(b[1], s, hh), 0.f);
            float a2 = fmaxf(fmaf(b[16], s, hh), 0.f);
            float a3 = fmaxf(fmaf(b[17], s, hh), 0.f);
            val = 0.25f * (a0 + a1 + a2 + a3);
        }
        img[i] = val;
    }
    // thread = (im, 2 w-px, 8 ch): im = t>>5; rem: p2 = rem>>2 (oh = p2>>1,
    // ow0 = (p2&1)*2), cg = rem&3
    const int im = t >> 5, rem = t & 31;
    const int p2 = rem >> 2, cg = rem & 3, c0 = cg * 8;
    const int oh = p2 >> 1, ow0 = (p2 & 1) * 2;
    double acc[2][8] = {};
    for (int phs = 0; phs < 2; ++phs) {
        __syncthreads();
        for (int i = t; i < 4608; i += 256) wt[i] = w3t[phs * 4608 + i];
        __syncthreads();
        for (int cp = 0; cp < 8; ++cp) {
            float prt[2][8] = {};
#pragma unroll
            for (int ch2 = 0; ch2 < 2; ++ch2) {
                const int ci = cp * 2 + ch2;
                const int cig = phs * 16 + ci;
#pragma unroll
                for (int th = 0; th < 3; ++th) {
                    const float* ip = &img[im * 1536 + cig * 48 + (oh + th) * 8];
                    float4 a = *(const float4*)ip;
                    float4 b = *(const float4*)(ip + 4);
                    float v[8] = {a.x, a.y, a.z, a.w, b.x, b.y, b.z, b.w};
#pragma unroll
                    for (int tw = 0; tw < 3; ++tw) {
                        const float* wp = &wt[(ci * 9 + th * 3 + tw) * 32 + c0];
                        float4 wa = *(const float4*)wp;
                        float4 wb = *(const float4*)(wp + 4);
                        float w8[8] = {wa.x, wa.y, wa.z, wa.w,
                                       wb.x, wb.y, wb.z, wb.w};
#pragma unroll
                        for (int j = 0; j < 2; ++j) {
                            float xv = v[ow0 + j + tw];
#pragma unroll
                            for (int c = 0; c < 8; ++c) prt[j][c] += xv * w8[c];
                        }
                    }
                }
            }
#pragma unroll
            for (int j = 0; j < 2; ++j)
#pragma unroll
                for (int c = 0; c < 8; ++c) acc[j][c] += (double)prt[j][c];
        }
    }
#pragma unroll
    for (int c = 0; c < 8; ++c) {
        float* dst = s3c + (size_t)(n0 + im) * 512 + (c0 + c) * 16 + oh * 4 + ow0;
        *(float2*)dst = make_float2((float)acc[0][c], (float)acc[1][c]);
    }
    double sm[8], sq[8];
#pragma unroll
    for (int c = 0; c < 8; ++c) {
        sm[c] = acc[0][c] + acc[1][c];
        sq[c] = acc[0][c] * acc[0][c] + acc[1][c] * acc[1][c];
    }
#pragma unroll
    for (int m = 4; m <= 32; m <<= 1)
#pragma unroll
        for (int c = 0; c < 8; ++c) {
            sm[c] += __shfl_xor(sm[c], m);
            sq[c] += __shfl_xor(sq[c], m);
        }
    const int wv = t >> 6, lane = t & 63;
    if (lane < 4) {
#pragma unroll
        for (int c = 0; c < 8; ++c) {
            red[wv][0][lane * 8 + c] = sm[c];
            red[wv][1][lane * 8 + c] = sq[c];
        }
    }
    __syncthreads();
    if (t < 64) {
        int which = t >> 5, ch = t & 31;
        part[(size_t)blockIdx.x * 64 + t] = red[0][which][ch] + red[1][which][ch] +
                                            red[2][which][ch] + red[3][which][ch];
    }
}

// ---------------------------------------------------------------------------
// K5: BN3(fp64)+relu+pool3 -> h0 NCHW-flat
// ---------------------------------------------------------------------------
__global__ void bn_pool3_h0(const float* __restrict__ s3c,
                            const double* __restrict__ scsh,
                            float* __restrict__ h0) {
    __shared__ double bn[64];
    const int t = threadIdx.x;
    if (t < 64) bn[t] = scsh[t];
    __syncthreads();
    const int idx = blockIdx.x * 256 + t;
    if (idx >= 262144) return;
    const int n = idx >> 7, rem = idx & 127;
    const int c = rem >> 2, q = rem & 3, ph = q >> 1, pw = q & 1;
    const float* b = s3c + (size_t)n * 512 + c * 16 + (2 * ph) * 4 + 2 * pw;
    const double s = bn[c], h = bn[32 + c];
    double a0 = fmax((double)b[0] * s + h, 0.0);
    double a1 = fmax((double)b[1] * s + h, 0.0);
    double a2 = fmax((double)b[4] * s + h, 0.0);
    double a3 = fmax((double)b[5] * s + h, 0.0);
    h0[idx] = (float)(0.25 * (a0 + a1 + a2 + a3));
}

// ---------------------------------------------------------------------------
// K6: beam level 0 (fp64)
// ---------------------------------------------------------------------------
__global__ void beam0_kernel(const float* __restrict__ h0, const float* __restrict__ Who,
                             const float* __restrict__ bho, double* __restrict__ scores,
                             int* __restrict__ op0, float* __restrict__ p0) {
    const int n = blockIdx.x, lane = threadIdx.x;
    const float* hr = h0 + (size_t)n * 128;
    double pt[4] = {};
    for (int i = lane; i < 128; i += 64) {
        double hv = hr[i];
        pt[0] += hv * (double)Who[i * 4 + 0];
        pt[1] += hv * (double)Who[i * 4 + 1];
        pt[2] += hv * (double)Who[i * 4 + 2];
        pt[3] += hv * (double)Who[i * 4 + 3];
    }
#pragma unroll
    for (int off = 32; off > 0; off >>= 1)
#pragma unroll
        for (int o = 0; o < 4; ++o) pt[o] += __shfl_down(pt[o], off);
    if (lane == 0) {
        double lg[4], e[4], probs[4], logp[4];
#pragma unroll
        for (int o = 0; o < 4; ++o) lg[o] = pt[o] + (double)bho[o];
        double m = fmax(fmax(lg[0], lg[1]), fmax(lg[2], lg[3]));
        double sum = 0.0;
#pragma unroll
        for (int o = 0; o < 4; ++o) { e[o] = exp(lg[o] - m); sum += e[o]; }
        double lse = log(sum);
#pragma unroll
        for (int o = 0; o < 4; ++o) {
            probs[o] = e[o] / sum;
            logp[o] = lg[o] - m - lse;
        }
        bool used[4] = {false, false, false, false};
        for (int slot = 0; slot < 4; ++slot) {
            int best = 0; double bv = -INFINITY;
            for (int o = 0; o < 4; ++o)
                if (!used[o] && logp[o] > bv) { bv = logp[o]; best = o; }
            used[best] = true;
            scores[n * 4 + slot] = bv;
            op0[n * 4 + slot] = best;
            p0[n * 4 + slot] = (float)probs[best];
        }
    }
}

// ---------------------------------------------------------------------------
// K8/K10: beam level >=1 (fp64)
// ---------------------------------------------------------------------------
__global__ void beam_level(const float* __restrict__ h, const float* __restrict__ Who,
                           const float* __restrict__ bho, double* __restrict__ scores,
                           int* __restrict__ opL, float* __restrict__ pL,
                           int* __restrict__ srcL) {
    __shared__ double logits[16], cand[16], pr[16];
    const int n = blockIdx.x, l = threadIdx.x;
    const int b = l >> 4, o = (l >> 2) & 3, qt = l & 3;
    const float* hr = h + ((size_t)n * 4 + b) * 128;
    double s = 0.0;
    for (int k = qt * 32; k < qt * 32 + 32; ++k)
        s += (double)hr[k] * (double)Who[k * 4 + o];
    s += __shfl_xor(s, 1);
    s += __shfl_xor(s, 2);
    if (qt == 0) logits[b * 4 + o] = s + (double)bho[o];
    __syncthreads();
    if (l < 4) {
        double lg[4];
#pragma unroll
        for (int o2 = 0; o2 < 4; ++o2) lg[o2] = logits[l * 4 + o2];
        double m = fmax(fmax(lg[0], lg[1]), fmax(lg[2], lg[3]));
        double e[4], sum = 0.0;
#pragma unroll
        for (int o2 = 0; o2 < 4; ++o2) { e[o2] = exp(lg[o2] - m); sum += e[o2]; }
        double lse = log(sum);
        double sb = scores[n * 4 + l];
#pragma unroll
        for (int o2 = 0; o2 < 4; ++o2) {
            pr[l * 4 + o2] = e[o2] / sum;
            cand[l * 4 + o2] = sb + (lg[o2] - m - lse);
        }
    }
    __syncthreads();
    if (l == 0) {
        bool used[16];
#pragma unroll
        for (int f = 0; f < 16; ++f) used[f] = false;
        double ns[4]; float np[4]; int nop[4], nsrc[4];
        for (int slot = 0; slot < 4; ++slot) {
            int best = 0; double bv = -INFINITY;
            for (int f = 0; f < 16; ++f)
                if (!used[f] && cand[f] > bv) { bv = cand[f]; best = f; }
            used[best] = true;
            ns[slot] = bv; nsrc[slot] = best >> 2; nop[slot] = best & 3;
            np[slot] = (float)pr[best];
        }
        for (int slot = 0; slot < 4; ++slot) {
            scores[n * 4 + slot] = ns[slot];
            opL[n * 4 + slot] = nop[slot];
            pL[n * 4 + slot] = np[slot];
            srcL[n * 4 + slot] = nsrc[slot];
        }
    }
}

// ---------------------------------------------------------------------------
// K7: h0_update — per-sample h0@Whh once, broadcast over 4 beams (fp64)
// ---------------------------------------------------------------------------
__global__ __launch_bounds__(256) void h0_update(
    const float* __restrict__ h0, const int* __restrict__ op0,
    const float* __restrict__ Whh, const float* __restrict__ Eop,
    const float* __restrict__ bh, float* __restrict__ out) {
    __shared__ float A[256];
    const int s0 = blockIdx.x * 2, t = threadIdx.x;
    const int row = t >> 7, j = t & 127;
    const int s = s0 + row;
    A[t] = h0[(size_t)s * 128 + j];
    __syncthreads();
    double acc = 0.0;
#pragma unroll 8
    for (int k = 0; k < 128; ++k)
        acc += (double)A[row * 128 + k] * (double)Whh[k * 128 + j];
    double base = acc + (double)bh[j];
#pragma unroll
    for (int b = 0; b < 4; ++b) {
        int op = op0[s * 4 + b];
        out[(size_t)(s * 4 + b) * 128 + j] =
            (float)tanh(base + (double)Eop[op * 128 + j]);
    }
}

// ---------------------------------------------------------------------------
// K9: h_update (srcL gather, fp64)
// ---------------------------------------------------------------------------
__global__ __launch_bounds__(256) void h_update(
    const float* __restrict__ in, const int* __restrict__ srcL,
    const int* __restrict__ opL, const float* __restrict__ Whh,
    const float* __restrict__ Eop, const float* __restrict__ bh,
    float* __restrict__ out) {
    __shared__ float A[256];
    const int r0 = blockIdx.x * 2, t = threadIdx.x;
    const int row = t >> 7, j = t & 127;
    const int r = r0 + row;
    const float* src = in + (size_t)((r & ~3) + srcL[r]) * 128;
    A[t] = src[j];
    __syncthreads();
    double acc = 0.0;
#pragma unroll 8
    for (int k = 0; k < 128; ++k)
        acc += (double)A[row * 128 + k] * (double)Whh[k * 128 + j];
    out[(size_t)r * 128 + j] =
        (float)tanh(acc + (double)Eop[opL[r] * 128 + j] + (double)bh[j]);
}

// ---------------------------------------------------------------------------
// K11: sort_ops — deterministic counting sort of rows by op (3 rounds)
// ---------------------------------------------------------------------------
__global__ __launch_bounds__(256) void sort_ops(
    const int* __restrict__ op0, const int* __restrict__ op1,
    const int* __restrict__ op2, int* __restrict__ perm,
    int* __restrict__ blkop, int* __restrict__ blkstart,
    int* __restrict__ blkcnt) {
    __shared__ int cnt[256][4];
    __shared__ int tot[4];
    __shared__ int base[4];
    const int t = threadIdx.x;
    for (int L = 0; L < 3; ++L) {
        const int* ops = (L == 0) ? op0 : (L == 1) ? op1 : op2;
        int c[4] = {0, 0, 0, 0};
        for (int i = 0; i < 32; ++i) c[ops[t * 32 + i]]++;
#pragma unroll
        for (int b = 0; b < 4; ++b) cnt[t][b] = c[b];
        __syncthreads();
        if (t < 4) {
            int s = 0;
            for (int u = 0; u < 256; ++u) { int v = cnt[u][t]; cnt[u][t] = s; s += v; }
            tot[t] = s;
        }
        __syncthreads();
        if (t == 0) {
            base[0] = 0;
            for (int b = 1; b < 4; ++b) base[b] = base[b - 1] + tot[b - 1];
        }
        __syncthreads();
        int off[4];
#pragma unroll
        for (int b = 0; b < 4; ++b) off[b] = cnt[t][b];
        for (int i = 0; i < 32; ++i) {
            int r = t * 32 + i, o = ops[r];
            perm[L * 8192 + base[o] + off[o]] = r;
            off[o]++;
        }
        if (t == 0) {
            int nb = 0;
            for (int o = 0; o < 4; ++o) {
                int cbin = tot[o], gb = base[o];
                for (int s = 0; s < cbin; s += 32) {
                    blkop[L * 272 + nb] = o;
                    blkstart[L * 272 + nb] = L * 8192 + gb + s;
                    blkcnt[L * 272 + nb] = (cbin - s < 32) ? (cbin - s) : 32;
                    nb++;
                }
            }
            for (; nb < 272; ++nb) blkop[L * 272 + nb] = -1;
        }
        __syncthreads();
    }
}

// ---------------------------------------------------------------------------
// K12/K13: dispatch_sorted — 32 same-op rows/block, expert weights in LDS
// ---------------------------------------------------------------------------
__global__ __launch_bounds__(256) void dispatch_sorted(
    const float* __restrict__ in, int mode, const int* __restrict__ perm,
    const int* __restrict__ blkop, const int* __restrict__ blkstart,
    const int* __restrict__ blkcnt, const float* __restrict__ pL,
    const float* __restrict__ expw, const float* __restrict__ expb,
    float* __restrict__ out) {
    __shared__ float As[32][128];
    __shared__ float Ws[64][128];
    __shared__ int rowid[32];
    __shared__ float rowp[32];
    const int b = blockIdx.x, t = threadIdx.x;
    const int op = blkop[b];
    if (op < 0) return;
    const int start = blkstart[b], cntv = blkcnt[b];
    if (t < 32) {
        int r = (t < cntv) ? perm[start + t] : -1;
        rowid[t] = r;
        rowp[t] = (r >= 0) ? pL[r] : 0.f;
    }
    __syncthreads();
    for (int i = t; i < 1024; i += 256) {
        int row = i >> 5, c4 = i & 31;
        int r = rowid[row];
        float4 v = make_float4(0.f, 0.f, 0.f, 0.f);
        if (r >= 0) {
            const float* src = (mode == 0) ? in + (size_t)(r >> 2) * 128
                                           : in + (size_t)r * 128;
            v = *(const float4*)(src + c4 * 4);
        }
        *(float4*)&As[row][c4 * 4] = v;
    }
    const int tr = (t >> 5) * 4, tc = (t & 31) * 4;
    float res[4][4];
    if (op < 3) {
        const float* W = expw + (size_t)op * 16384;
        float acc[4][4] = {};
        for (int ph = 0; ph < 2; ++ph) {
            __syncthreads();
            for (int i = t; i < 2048; i += 256)
                ((float4*)Ws)[i] = ((const float4*)(W + ph * 8192))[i];
            __syncthreads();
            for (int k = 0; k < 64; ++k) {
                float a0 = As[tr + 0][ph * 64 + k];
                float a1 = As[tr + 1][ph * 64 + k];
                float a2 = As[tr + 2][ph * 64 + k];
                float a3 = As[tr + 3][ph * 64 + k];
                float4 w = *(const float4*)&Ws[k][tc];
                acc[0][0] += a0 * w.x; acc[0][1] += a0 * w.y;
                acc[0][2] += a0 * w.z; acc[0][3] += a0 * w.w;
                acc[1][0] += a1 * w.x; acc[1][1] += a1 * w.y;
                acc[1][2] += a1 * w.z; acc[1][3] += a1 * w.w;
                acc[2][0] += a2 * w.x; acc[2][1] += a2 * w.y;
                acc[2][2] += a2 * w.z; acc[2][3] += a2 * w.w;
                acc[3][0] += a3 * w.x; acc[3][1] += a3 * w.y;
                acc[3][2] += a3 * w.z; acc[3][3] += a3 * w.w;
            }
        }
        float4 eb = *(const float4*)&expb[op * 128 + tc];
#pragma unroll
        for (int i = 0; i < 4; ++i) {
            float p = rowp[tr + i];
            res[i][0] = fmaxf((acc[i][0] + eb.x) * p, 0.f);
            res[i][1] = fmaxf((acc[i][1] + eb.y) * p, 0.f);
            res[i][2] = fmaxf((acc[i][2] + eb.z) * p, 0.f);
            res[i][3] = fmaxf((acc[i][3] + eb.w) * p, 0.f);
        }
    } else {
        __syncthreads();
#pragma unroll
        for (int i = 0; i < 4; ++i) {
            float p = rowp[tr + i];
#pragma unroll
            for (int jj = 0; jj < 4; ++jj)
                res[i][jj] = fmaxf(As[tr + i][tc + jj] * p, 0.f);
        }
    }
#pragma unroll
    for (int i = 0; i < 4; ++i) {
        int r = rowid[tr + i];
        if (r >= 0)
            *(float4*)(out + (size_t)r * 128 + tc) =
                make_float4(res[i][0], res[i][1], res[i][2], res[i][3]);
    }
}

// ---------------------------------------------------------------------------
// K14: dispatch round 3 with fused final head (8192 x 10 -> d_out)
// ---------------------------------------------------------------------------
__global__ __launch_bounds__(256) void dispatch_sorted_final(
    const float* __restrict__ in, const int* __restrict__ perm,
    const int* __restrict__ blkop, const int* __restrict__ blkstart,
    const int* __restrict__ blkcnt, const float* __restrict__ pL,
    const float* __restrict__ expw, const float* __restrict__ expb,
    const float* __restrict__ ow, const float* __restrict__ ob,
    float* __restrict__ dout) {
    __shared__ float As[32][128];
    __shared__ float Ws[64][128];
    __shared__ int rowid[32];
    __shared__ float rowp[32];
    const int b = blockIdx.x, t = threadIdx.x;
    const int op = blkop[b];
    if (op < 0) return;
    const int start = blkstart[b], cntv = blkcnt[b];
    if (t < 32) {
        int r = (t < cntv) ? perm[start + t] : -1;
        rowid[t] = r;
        rowp[t] = (r >= 0) ? pL[r] : 0.f;
    }
    __syncthreads();
    for (int i = t; i < 1024; i += 256) {
        int row = i >> 5, c4 = i & 31;
        int r = rowid[row];
        float4 v = make_float4(0.f, 0.f, 0.f, 0.f);
        if (r >= 0) v = *(const float4*)(in + (size_t)r * 128 + c4 * 4);
        *(float4*)&As[row][c4 * 4] = v;
    }
    const int tr = (t >> 5) * 4, tc = (t & 31) * 4;
    float res[4][4];
    if (op < 3) {
        const float* W = expw + (size_t)op * 16384;
        float acc[4][4] = {};
        for (int ph = 0; ph < 2; ++ph) {
            __syncthreads();
            for (int i = t; i < 2048; i += 256)
                ((float4*)Ws)[i] = ((const float4*)(W + ph * 8192))[i];
            __syncthreads();
            for (int k = 0; k < 64; ++k) {
                float a0 = As[tr + 0][ph * 64 + k];
                float a1 = As[tr + 1][ph * 64 + k];
                float a2 = As[tr + 2][ph * 64 + k];
                float a3 = As[tr + 3][ph * 64 + k];
                float4 w = *(const float4*)&Ws[k][tc];
                acc[0][0] += a0 * w.x; acc[0][1] += a0 * w.y;
                acc[0][2] += a0 * w.z; acc[0][3] += a0 * w.w;
                acc[1][0] += a1 * w.x; acc[1][1] += a1 * w.y;
                acc[1][2] += a1 * w.z; acc[1][3] += a1 * w.w;
                acc[2][0] += a2 * w.x; acc[2][1] += a2 * w.y;
                acc[2][2] += a2 * w.z; acc[2][3] += a2 * w.w;
                acc[3][0] += a3 * w.x; acc[3][1] += a3 * w.y;
                acc[3][2] += a3 * w.z; acc[3][3] += a3 * w.w;
            }
        }
        float4 eb = *(const float4*)&expb[op * 128 + tc];
#pragma unroll
        for (int i = 0; i < 4; ++i) {
            float p = rowp[tr + i];
            res[i][0] = fmaxf((acc[i][0] + eb.x) * p, 0.f);
            res[i][1] = fmaxf((acc[i][1] + eb.y) * p, 0.f);
            res[i][2] = fmaxf((acc[i][2] + eb.z) * p, 0.f);
            res[i][3] = fmaxf((acc[i][3] + eb.w) * p, 0.f);
        }
    } else {
        __syncthreads();
#pragma unroll
        for (int i = 0; i < 4; ++i) {
            float p = rowp[tr + i];
#pragma unroll
            for (int jj = 0; jj < 4; ++jj)
                res[i][jj] = fmaxf(As[tr + i][tc + jj] * p, 0.f);
        }
    }
    __syncthreads();
#pragma unroll
    for (int i = 0; i < 4; ++i)
        *(float4*)&As[tr + i][tc] =
            make_float4(res[i][0], res[i][1], res[i][2], res[i][3]);
    __syncthreads();
    for (int u = t; u < 320; u += 256) {
        int row = u / 10, o = u % 10;
        int r = rowid[row];
        if (r < 0) continue;
        float acc2 = ob[o];
#pragma unroll 8
        for (int k = 0; k < 128; ++k) acc2 += As[row][k] * ow[k * 10 + o];
        dout[(size_t)r * 10 + o] = acc2;
    }
}

// ===========================================================================
extern "C" void kernel_launch(void* const* d_in, const int* in_sizes, int n_in,
                              void* d_out, int out_size, void* d_ws, size_t ws_size,
                              hipStream_t stream) {
    const float* x    = (const float*)d_in[0];
    const float* cw1  = (const float*)d_in[1];
    const float* g1   = (const float*)d_in[3];
    const float* be1  = (const float*)d_in[4];
    const float* cw2  = (const float*)d_in[5];
    const float* g2   = (const float*)d_in[7];
    const float* be2  = (const float*)d_in[8];
    const float* cw3  = (const float*)d_in[9];
    const float* g3   = (const float*)d_in[11];
    const float* be3  = (const float*)d_in[12];
    const float* Whh  = (const float*)d_in[13];
    const float* bh   = (const float*)d_in[14];
    const float* Eop  = (const float*)d_in[15];
    const float* Who  = (const float*)d_in[16];
    const float* bho  = (const float*)d_in[17];
    const float* expw = (const float*)d_in[18];
    const float* expb = (const float*)d_in[19];
    const float* outw = (const float*)d_in[20];
    const float* outb = (const float*)d_in[21];
    float*  ws    = (float*)d_ws;
    float*  out   = (float*)d_out;
    double* scsh  = (double*)(ws + O_SC);
    double* part  = (double*)(ws + O_PART);
    double* score = (double*)(ws + O_SCORES);
    int* perm   = (int*)(ws + O_PERM);
    int* blkop  = (int*)(ws + O_BLKOP);
    int* blkst  = (int*)(ws + O_BLKST);
    int* blkct  = (int*)(ws + O_BLKCT);

    prep_w<<<36, 256, 0, stream>>>(cw1, cw2, cw3, ws + O_W1T, ws + O_W2T, ws + O_W3T);

    // ---- backbone ----
    conv1_stats_kernel<<<2048, 256, 0, stream>>>(x, ws + O_W1T, part);
    finalize_stats<<<1, 256, 0, stream>>>(part, 2048, 1.0 / 1843200.0, g1, be1, scsh);
    conv1_apply_kernel<<<2048, 512, 0, stream>>>(x, ws + O_W1T, scsh, ws + O_S1P);
    conv2_kernel<<<2048, 256, 0, stream>>>(ws + O_S1P, ws + O_W2T, ws + O_S2C, part);
    finalize_stats<<<1, 256, 0, stream>>>(part, 2048, 1.0 / 346112.0, g2, be2, scsh + 64);
    conv3_kernel<<<256, 256, 0, stream>>>(ws + O_S2C, ws + O_W3T, scsh + 64,
                                          ws + O_S3C, part);
    finalize_stats<<<1, 256, 0, stream>>>(part, 256, 1.0 / 32768.0, g3, be3, scsh + 128);
    bn_pool3_h0<<<1024, 256, 0, stream>>>(ws + O_S3C, scsh + 128, ws + O_H0);

    // ---- beam search ----
    beam0_kernel<<<2048, 64, 0, stream>>>(ws + O_H0, Who, bho, score,
                                          (int*)(ws + O_OP0), ws + O_P0);
    h0_update<<<1024, 256, 0, stream>>>(ws + O_H0, (int*)(ws + O_OP0),
                                        Whh, Eop, bh, ws + O_H);
    beam_level<<<2048, 64, 0, stream>>>(ws + O_H, Who, bho, score,
                                        (int*)(ws + O_OP1), ws + O_P1,
                                        (int*)(ws + O_SRC1));
    h_update<<<4096, 256, 0, stream>>>(ws + O_H, (int*)(ws + O_SRC1),
                                       (int*)(ws + O_OP1), Whh, Eop, bh, ws + O_H2);
    beam_level<<<2048, 64, 0, stream>>>(ws + O_H2, Who, bho, score,
                                        (int*)(ws + O_OP2), ws + O_P2,
                                        (int*)(ws + O_SRC2));

    // ---- sorted expert dispatch (3 rounds; round 3 fuses the head) ----
    sort_ops<<<1, 256, 0, stream>>>((int*)(ws + O_OP0), (int*)(ws + O_OP1),
                                    (int*)(ws + O_OP2), perm, blkop, blkst, blkct);
    dispatch_sorted<<<260, 256, 0, stream>>>(ws + O_H0, 0, perm, blkop, blkst,
                                             blkct, ws + O_P0, expw, expb,
                                             ws + O_HIDA);
    dispatch_sorted<<<260, 256, 0, stream>>>(ws + O_HIDA, 1, perm, blkop + 272,
                                             blkst + 272, blkct + 272, ws + O_P1,
                                             expw, expb, ws + O_HIDB);
    dispatch_sorted_final<<<260, 256, 0, stream>>>(ws + O_HIDB, perm, blkop + 544,
                                                   blkst + 544, blkct + 544,
                                                   ws + O_P2, expw, expb,
                                                   outw, outb, out);
}